// Round 9
// baseline (571.197 us; speedup 1.0000x reference)
//
#include <hip/hip_runtime.h>
#include <hip/hip_bf16.h>
#include <math.h>

// Problem constants (AutoCorrelationAttention): B=8, L=4096, E=1024, H=16, D=64
#define B_ 8
#define L_ 4096
#define E_ 1024
#define H_ 16
#define D_ 64

typedef short short8 __attribute__((ext_vector_type(8)));
typedef float f32x4 __attribute__((ext_vector_type(4)));

__device__ __forceinline__ unsigned short f2bf(float f) {
  unsigned int u = __float_as_uint(f);
  unsigned int r = u + 0x7FFFu + ((u >> 16) & 1u);
  return (unsigned short)(r >> 16);
}
__device__ __forceinline__ float bf2f(unsigned short h) {
  return __uint_as_float(((unsigned int)h) << 16);
}

#define GLDS16(g, l)                                                     \
  __builtin_amdgcn_global_load_lds(                                      \
      (const __attribute__((address_space(1))) void*)(g),                \
      (__attribute__((address_space(3))) void*)(l), 16, 0, 0)

// ---------------------------------------------------------------------------
// Kernel 0a: convert Wq/Wk/Wv to bf16 (rounded), fused [3072][1024] layout.
// ---------------------------------------------------------------------------
__global__ __launch_bounds__(256) void conv_w(
    const float* __restrict__ Wq, const float* __restrict__ Wk,
    const float* __restrict__ Wv, unsigned short* __restrict__ Wb) {
  const int wsel = blockIdx.y;
  const float* W = (wsel == 0) ? Wq : (wsel == 1) ? Wk : Wv;
  size_t i = ((size_t)blockIdx.x * 256 + threadIdx.x) * 4;
  float4 f = *(const float4*)(W + i);
  size_t o = (size_t)wsel * (1024 * 1024) + i;
  *(ushort4*)(Wb + o) =
      make_ushort4(f2bf(f.x), f2bf(f.y), f2bf(f.z), f2bf(f.w));
}

// ---------------------------------------------------------------------------
// Kernel 0b: convert x (fp32) -> xb (bf16, rounded), natural layout.
// ---------------------------------------------------------------------------
__global__ __launch_bounds__(256) void conv_x(const float* __restrict__ x,
                                              unsigned short* __restrict__ xb) {
  const size_t total = (size_t)B_ * L_ * E_ / 8;
  for (size_t i = (size_t)blockIdx.x * blockDim.x + threadIdx.x; i < total;
       i += (size_t)gridDim.x * blockDim.x) {
    float4 a = ((const float4*)x)[i * 2];
    float4 b = ((const float4*)x)[i * 2 + 1];
    short8 v;
    v[0] = (short)f2bf(a.x); v[1] = (short)f2bf(a.y);
    v[2] = (short)f2bf(a.z); v[3] = (short)f2bf(a.w);
    v[4] = (short)f2bf(b.x); v[5] = (short)f2bf(b.y);
    v[6] = (short)f2bf(b.z); v[7] = (short)f2bf(b.w);
    *(short8*)&xb[i * 8] = v;
  }
}

// ---------------------------------------------------------------------------
// Kernel 1: fused QKV projection — 256x256 8-phase bf16 MFMA GEMM (T2+T3+T4+T5)
// (unchanged from R8 — verified, conflicts 0)
// ---------------------------------------------------------------------------
#define STAGE_A(buf, h, s, t)                                                \
  GLDS16(xb + (size_t)(m0 + (s)*128 + (h)*64 + srow) * E_ + (t)*64 + scol,   \
         &sA[buf][((s)*128 + (h)*64 + wid * 8) * 64])
#define STAGE_B(buf, h, s, t)                                                \
  GLDS16(Wb + (size_t)(n0 + (s)*128 + (h)*32 + brow_i) * E_ + (t)*64 + scol, \
         &sB[buf][((s)*128 + (h)*32 + bw) * 64])

#define PHASE(mh, nh, STAGE)                                                  \
  {                                                                           \
    short8 af[4][2], bfr[2][2];                                               \
    _Pragma("unroll") for (int i = 0; i < 4; ++i)                             \
    _Pragma("unroll") for (int kk = 0; kk < 2; ++kk) {                        \
      const int blk = (((kk * 4 + fg) ^ fr7) << 3);                           \
      af[i][kk] = *(const short8*)                                            \
          &sA[cur][(wr * 128 + ((mh)*4 + i) * 16 + fr) * 64 + blk];           \
    }                                                                         \
    _Pragma("unroll") for (int j = 0; j < 2; ++j)                             \
    _Pragma("unroll") for (int kk = 0; kk < 2; ++kk) {                        \
      const int blk = (((kk * 4 + fg) ^ fr7) << 3);                           \
      bfr[j][kk] = *(const short8*)                                           \
          &sB[cur][(wc * 64 + ((nh)*2 + j) * 16 + fr) * 64 + blk];            \
    }                                                                         \
    STAGE;                                                                    \
    __builtin_amdgcn_s_barrier();                                             \
    asm volatile("s_waitcnt lgkmcnt(0)" ::: "memory");                        \
    __builtin_amdgcn_sched_barrier(0);                                        \
    __builtin_amdgcn_s_setprio(1);                                            \
    _Pragma("unroll") for (int i = 0; i < 4; ++i)                             \
    _Pragma("unroll") for (int j = 0; j < 2; ++j)                             \
    _Pragma("unroll") for (int kk = 0; kk < 2; ++kk)                          \
      acc[(mh)*4 + i][(nh)*2 + j] = __builtin_amdgcn_mfma_f32_16x16x32_bf16(  \
          af[i][kk], bfr[j][kk], acc[(mh)*4 + i][(nh)*2 + j], 0, 0, 0);       \
    __builtin_amdgcn_s_setprio(0);                                            \
    __builtin_amdgcn_s_barrier();                                             \
  }

__global__ __launch_bounds__(512) void qkv_gemm8(
    const unsigned short* __restrict__ xb,
    const unsigned short* __restrict__ Wb, const float* __restrict__ bq,
    const float* __restrict__ bk, const float* __restrict__ bv,
    unsigned short* __restrict__ QTb, unsigned short* __restrict__ KTb,
    unsigned short* __restrict__ Vb) {
  __shared__ unsigned short sA[2][256 * 64];  // 2 x 32 KB
  __shared__ unsigned short sB[2][256 * 64];  // 2 x 32 KB

  const int tid = threadIdx.x;
  const int wid = tid >> 6, lane = tid & 63;
  const int wr = wid >> 2, wc = wid & 3;
  const int fr = lane & 15, fg = lane >> 4, fr7 = fr & 7;
  const int n0 = blockIdx.x * 256;
  const int m0 = blockIdx.y * 256;

  const int srow = tid >> 3;
  const int scol = ((tid & 7) ^ (srow & 7)) * 8;
  const int brow_i = ((srow >> 5) << 6) + (srow & 31);
  const int bw = ((wid >> 2) << 6) + ((wid & 3) << 3);

  f32x4 acc[8][4];
#pragma unroll
  for (int i = 0; i < 8; ++i)
#pragma unroll
    for (int j = 0; j < 4; ++j) acc[i][j] = (f32x4){0.f, 0.f, 0.f, 0.f};

  STAGE_A(0, 0, 0, 0); STAGE_A(0, 0, 1, 0);
  STAGE_B(0, 0, 0, 0); STAGE_B(0, 0, 1, 0);
  STAGE_A(0, 1, 0, 0); STAGE_A(0, 1, 1, 0);
  STAGE_B(0, 1, 0, 0); STAGE_B(0, 1, 1, 0);
  STAGE_A(1, 0, 0, 1); STAGE_A(1, 0, 1, 1);
  STAGE_B(1, 0, 0, 1); STAGE_B(1, 0, 1, 1);

  const int NT = E_ / 64;
  for (int u = 0; u < NT; ++u) {
    const int cur = u & 1, nxt = cur ^ 1;
    __builtin_amdgcn_sched_barrier(0);
    if (u == NT - 1)
      asm volatile("s_waitcnt vmcnt(0)" ::: "memory");
    else
      asm volatile("s_waitcnt vmcnt(4)" ::: "memory");
    __builtin_amdgcn_sched_barrier(0);
    __builtin_amdgcn_s_barrier();
    PHASE(0, 0, if (u + 1 < NT) { STAGE_A(nxt, 1, 0, u + 1); STAGE_A(nxt, 1, 1, u + 1); })
    PHASE(0, 1, if (u + 1 < NT) { STAGE_B(nxt, 1, 0, u + 1); STAGE_B(nxt, 1, 1, u + 1); })
    PHASE(1, 0, if (u + 2 < NT) { STAGE_A(cur, 0, 0, u + 2); STAGE_A(cur, 0, 1, u + 2); })
    PHASE(1, 1, if (u + 2 < NT) { STAGE_B(cur, 0, 0, u + 2); STAGE_B(cur, 0, 1, u + 2); })
  }

  const int wsel = n0 >> 10;
  const float* bias = (wsel == 0) ? bq : (wsel == 1) ? bk : bv;
  float br[4];
#pragma unroll
  for (int j = 0; j < 4; ++j)
    br[j] = bias[(n0 & 1023) + wc * 64 + j * 16 + fr];

  if (wsel < 2) {
    unsigned short* T = (wsel == 0) ? QTb : KTb;
    const int b = m0 >> 12;
    const int lbase = (m0 & 4095) + wr * 128 + (fg << 2);
#pragma unroll
    for (int i = 0; i < 8; ++i)
#pragma unroll
      for (int j = 0; j < 4; ++j) {
        const int n_in = (n0 & 1023) + wc * 64 + j * 16 + fr;
        ushort4 v = make_ushort4(f2bf(acc[i][j][0] + br[j]),
                                 f2bf(acc[i][j][1] + br[j]),
                                 f2bf(acc[i][j][2] + br[j]),
                                 f2bf(acc[i][j][3] + br[j]));
        *(ushort4*)&T[((size_t)(b << 10) + n_in) * L_ + lbase + i * 16] = v;
      }
  } else {
#pragma unroll
    for (int i = 0; i < 8; ++i)
#pragma unroll
      for (int j = 0; j < 4; ++j) {
        const int n_in = (n0 & 1023) + wc * 64 + j * 16 + fr;
#pragma unroll
        for (int r = 0; r < 4; ++r) {
          const int m = m0 + wr * 128 + i * 16 + (fg << 2) + r;
          Vb[(size_t)m * E_ + n_in] = f2bf(acc[i][j][r] + br[j]);
        }
      }
  }
}

// ---------------------------------------------------------------------------
// Complex helpers shared by both FFT variants.
// ---------------------------------------------------------------------------
__device__ __forceinline__ float2 cmulf(float2 a, float2 b) {
  return make_float2(a.x * b.x - a.y * b.y, a.x * b.y + a.y * b.x);
}

// ---------------------------------------------------------------------------
// Radix-16 in-register machinery (corr_fft).  4096 = 16^3 -> 3 LDS stages.
// LDS float2 index swizzle: phys = i ^ ((i>>4)&15)  (involution, both sides).
// ---------------------------------------------------------------------------
__device__ __forceinline__ int swz(int i) { return i ^ ((i >> 4) & 15); }

__device__ __forceinline__ void dft4(float2& a, float2& b, float2& c,
                                     float2& d, float sign) {
  float2 t0 = make_float2(a.x + c.x, a.y + c.y);
  float2 t1 = make_float2(a.x - c.x, a.y - c.y);
  float2 t2 = make_float2(b.x + d.x, b.y + d.y);
  float2 t3 = make_float2(b.x - d.x, b.y - d.y);
  float2 t3i = make_float2(-sign * t3.y, sign * t3.x);
  a = make_float2(t0.x + t2.x, t0.y + t2.y);
  b = make_float2(t1.x + t3i.x, t1.y + t3i.y);
  c = make_float2(t0.x - t2.x, t0.y - t2.y);
  d = make_float2(t1.x - t3i.x, t1.y - t3i.y);
}

// v * (c + i*sign*s)
__device__ __forceinline__ float2 twc(float2 v, float c, float s, float sign) {
  return make_float2(v.x * c - v.y * s * sign, v.x * s * sign + v.y * c);
}

#define C16_1 0.923879532511287f
#define S16_1 0.382683432365090f
#define C16_2 0.707106781186548f

// 16-point DFT, v[m] in natural order; output X[q+4p] lands at v[p+4q].
__device__ __forceinline__ void dft16(float2 v[16], float sign) {
  // layer 1: DFT4 over m2 (v[m1+4m2]) for each m1
  dft4(v[0], v[4], v[8], v[12], sign);
  dft4(v[1], v[5], v[9], v[13], sign);
  dft4(v[2], v[6], v[10], v[14], sign);
  dft4(v[3], v[7], v[11], v[15], sign);
  // twiddle: v[m1+4q] *= W16^(m1*q)
  v[5]  = twc(v[5],  C16_1,  S16_1, sign);   // e=1
  v[9]  = twc(v[9],  C16_2,  C16_2, sign);   // e=2
  v[13] = twc(v[13], S16_1,  C16_1, sign);   // e=3
  v[6]  = twc(v[6],  C16_2,  C16_2, sign);   // e=2
  v[10] = twc(v[10], 0.0f,   1.0f,  sign);   // e=4
  v[14] = twc(v[14], -C16_2, C16_2, sign);   // e=6
  v[7]  = twc(v[7],  S16_1,  C16_1, sign);   // e=3
  v[11] = twc(v[11], -C16_2, C16_2, sign);   // e=6
  v[15] = twc(v[15], -C16_1, -S16_1, sign);  // e=9
  // layer 2: DFT4 over m1 (v[m1+4q]) for each q
  dft4(v[0], v[1], v[2], v[3], sign);
  dft4(v[4], v[5], v[6], v[7], sign);
  dft4(v[8], v[9], v[10], v[11], sign);
  dft4(v[12], v[13], v[14], v[15], sign);
}

// One radix-16 Stockham stage: reads src[tid+256m], writes 16 outputs.
template <int NS, bool TW>
__device__ __forceinline__ void fft16_stage(const float2* __restrict__ src,
                                            float2* __restrict__ dst,
                                            const float2* __restrict__ tw,
                                            int tid, float sign) {
  float2 v[16];
#pragma unroll
  for (int m = 0; m < 16; ++m) v[m] = src[swz(tid + (m << 8))];
  if (TW) {
#pragma unroll
    for (int m = 1; m < 16; ++m) v[m] = cmulf(v[m], tw[m - 1]);
  }
  dft16(v, sign);
  const int r = tid & (NS - 1);
  const int base = ((tid - r) << 4) + r;  // (tid/NS)*16*NS + r
#pragma unroll
  for (int o = 0; o < 16; ++o)
    dst[swz(base + o * NS)] = v[((o & 3) << 2) | (o >> 2)];
}

// ---------------------------------------------------------------------------
// Kernel 2a: per-(b,h,ds) partial cross-spectrum. 8 packed FFTs per block.
// 256 threads; 3 radix-16 stages; twiddles precomputed (reused across FFTs).
// LDS 80 KB -> 2 blocks/CU.
// ---------------------------------------------------------------------------
__global__ __launch_bounds__(256) void corr_fft(
    const unsigned short* __restrict__ QTb,
    const unsigned short* __restrict__ KTb, float2* __restrict__ Spart) {
  __shared__ float2 bufA[L_];      // 32 KB
  __shared__ float2 bufB[L_];      // 32 KB
  __shared__ float2 S[L_ / 2];     // 16 KB (Nyquist packed into S[0].y)

  const int bh = blockIdx.x, ds = blockIdx.y;
  const int b = bh >> 4, h = bh & (H_ - 1);
  const int tid = threadIdx.x;
  const float sign = -1.0f;

  // inter-stage twiddles: stage1 base exp(-2pi*i*(tid&15)/256),
  //                       stage2 base exp(-2pi*i*tid/4096); powers 1..15.
  float2 tw1[15], tw2[15];
  {
    const float TWO_PI = 6.28318530717958647692f;
    float s, c;
    __sincosf(sign * TWO_PI * (float)(tid & 15) / 256.f, &s, &c);
    tw1[0] = make_float2(c, s);
    __sincosf(sign * TWO_PI * (float)tid / 4096.f, &s, &c);
    tw2[0] = make_float2(c, s);
#pragma unroll
    for (int m = 1; m < 15; ++m) {
      tw1[m] = cmulf(tw1[m - 1], tw1[0]);
      tw2[m] = cmulf(tw2[m - 1], tw2[0]);
    }
  }

  for (int f = tid; f < L_ / 2; f += 256) S[f] = make_float2(0.f, 0.f);

  const size_t baseQK = (size_t)(b * E_ + h * D_) * L_;
  const int p0 = tid << 4;

  // load dd=0 into bufA (swizzled)
  {
    const unsigned short* q = QTb + baseQK + (size_t)(ds * 8) * L_;
    const unsigned short* k = KTb + baseQK + (size_t)(ds * 8) * L_;
#pragma unroll
    for (int c4 = 0; c4 < 4; ++c4) {
      ushort4 q4 = *(const ushort4*)(q + p0 + c4 * 4);
      ushort4 k4 = *(const ushort4*)(k + p0 + c4 * 4);
      bufA[swz(p0 + c4 * 4 + 0)] = make_float2(bf2f(q4.x), bf2f(k4.x));
      bufA[swz(p0 + c4 * 4 + 1)] = make_float2(bf2f(q4.y), bf2f(k4.y));
      bufA[swz(p0 + c4 * 4 + 2)] = make_float2(bf2f(q4.z), bf2f(k4.z));
      bufA[swz(p0 + c4 * 4 + 3)] = make_float2(bf2f(q4.w), bf2f(k4.w));
    }
  }

  for (int dd = 0; dd < 8; ++dd) {
    __syncthreads();
    fft16_stage<1, false>(bufA, bufB, tw1, tid, sign);
    __syncthreads();
    fft16_stage<16, true>(bufB, bufA, tw1, tid, sign);
    __syncthreads();
    fft16_stage<256, true>(bufA, bufB, tw2, tid, sign);
    __syncthreads();
    // Hermitian split + accumulate (reads bufB); overlap next-tile load
    // (writes bufA) in the same region — independent buffers.
    for (int f = tid; f <= L_ / 2; f += 256) {
      float2 Zf = bufB[swz(f)];
      float2 Zc = bufB[swz((L_ - f) & (L_ - 1))];
      float ax = Zc.x, ay = -Zc.y;
      float qx = 0.5f * (Zf.x + ax), qy = 0.5f * (Zf.y + ay);
      float ux = Zf.x - ax, uy = Zf.y - ay;
      float kx = 0.5f * uy, ky = -0.5f * ux;
      float re = qx * kx + qy * ky;
      float im = qy * kx - qx * ky;
      if (f == 0) S[0].x += re;
      else if (f == L_ / 2) S[0].y += re;
      else { S[f].x += re; S[f].y += im; }
    }
    if (dd < 7) {
      const int d = ds * 8 + dd + 1;
      const unsigned short* q = QTb + baseQK + (size_t)d * L_;
      const unsigned short* k = KTb + baseQK + (size_t)d * L_;
#pragma unroll
      for (int c4 = 0; c4 < 4; ++c4) {
        ushort4 q4 = *(const ushort4*)(q + p0 + c4 * 4);
        ushort4 k4 = *(const ushort4*)(k + p0 + c4 * 4);
        bufA[swz(p0 + c4 * 4 + 0)] = make_float2(bf2f(q4.x), bf2f(k4.x));
        bufA[swz(p0 + c4 * 4 + 1)] = make_float2(bf2f(q4.y), bf2f(k4.y));
        bufA[swz(p0 + c4 * 4 + 2)] = make_float2(bf2f(q4.z), bf2f(k4.z));
        bufA[swz(p0 + c4 * 4 + 3)] = make_float2(bf2f(q4.w), bf2f(k4.w));
      }
    }
  }
  __syncthreads();
  float2* out = Spart + (size_t)(bh * 8 + ds) * (L_ / 2);
  for (int f = tid; f < L_ / 2; f += 256) out[f] = S[f];
}

// ---------------------------------------------------------------------------
// Radix-4 Stockham (corr_post, 1024 threads) — unchanged.
// ---------------------------------------------------------------------------
__device__ __forceinline__ void fft_tw_init(float2* tw, int tid, float sign) {
  const float TWO_PI = 6.28318530717958647692f;
#pragma unroll
  for (int st = 0; st < 6; ++st) {
    const int Ns = 1 << (2 * st);
    const int r = tid & (Ns - 1);
    float ang = sign * TWO_PI * (float)r / (float)(4 * Ns);
    __sincosf(ang, &tw[st].y, &tw[st].x);
  }
}

__device__ __forceinline__ void fft4096_tw(float2* __restrict__ A,
                                           float2* __restrict__ Bb, int tid,
                                           float sign,
                                           const float2* __restrict__ tw) {
  float2* cur = A;
  float2* nxt = Bb;
#pragma unroll
  for (int st = 0; st < 6; ++st) {
    const int Ns = 1 << (2 * st);
    __syncthreads();
    const int j = tid;
    float2 v0 = cur[j];
    float2 v1 = cur[j + 1024];
    float2 v2 = cur[j + 2048];
    float2 v3 = cur[j + 3072];
    const int r = j & (Ns - 1);
    if (st > 0) {
      float2 w1 = tw[st];
      float2 w2 = cmulf(w1, w1);
      float2 w3 = cmulf(w2, w1);
      v1 = cmulf(v1, w1);
      v2 = cmulf(v2, w2);
      v3 = cmulf(v3, w3);
    }
    float2 t0 = make_float2(v0.x + v2.x, v0.y + v2.y);
    float2 t1 = make_float2(v0.x - v2.x, v0.y - v2.y);
    float2 t2 = make_float2(v1.x + v3.x, v1.y + v3.y);
    float2 t3 = make_float2(v1.x - v3.x, v1.y - v3.y);
    float2 t3i = make_float2(-sign * t3.y, sign * t3.x);
    const int idxD = ((j - r) << 2) + r;
    nxt[idxD]          = make_float2(t0.x + t2.x, t0.y + t2.y);
    nxt[idxD + Ns]     = make_float2(t1.x + t3i.x, t1.y + t3i.y);
    nxt[idxD + 2 * Ns] = make_float2(t0.x - t2.x, t0.y - t2.y);
    nxt[idxD + 3 * Ns] = make_float2(t1.x - t3i.x, t1.y - t3i.y);
    float2* tmp = cur; cur = nxt; nxt = tmp;
  }
  __syncthreads();
}

// ---------------------------------------------------------------------------
// Kernel 2b: per-(b,h) reduce partials -> inverse FFT -> softmax -> attn@V.
// ---------------------------------------------------------------------------
__global__ __launch_bounds__(1024) void corr_post(
    const float2* __restrict__ Spart, const unsigned short* __restrict__ Vb,
    float* __restrict__ out_flat) {
  __shared__ float2 bufA[L_];
  __shared__ float2 bufB[L_];
  __shared__ float red[1024];

  const int bh = blockIdx.x;
  const int b = bh >> 4, h = bh & (H_ - 1);
  const int tid = threadIdx.x;

  float2 tw[6];
  fft_tw_init(tw, tid, 1.0f);

  const float2* sp = Spart + (size_t)(bh * 8) * (L_ / 2);
  for (int f = tid; f < L_ / 2; f += 1024) {
    float2 s = make_float2(0.f, 0.f);
#pragma unroll
    for (int ds = 0; ds < 8; ++ds) {
      float2 p = sp[(size_t)ds * (L_ / 2) + f];
      s.x += p.x;
      s.y += p.y;
    }
    if (f == 0) {
      bufA[0] = make_float2(s.x, 0.f);
      bufA[L_ / 2] = make_float2(s.y, 0.f);
    } else {
      bufA[f] = s;
      bufA[L_ - f] = make_float2(s.x, -s.y);
    }
  }
  fft4096_tw(bufA, bufB, tid, 1.0f, tw);

  const float cscale = 1.0f / ((float)L_ * (float)D_);
  float lmax = -3.0e38f;
#pragma unroll
  for (int q = 0; q < 4; ++q) lmax = fmaxf(lmax, bufA[tid + q * 1024].x);
  red[tid] = lmax;
  __syncthreads();
  for (int s = 512; s > 0; s >>= 1) {
    if (tid < s) red[tid] = fmaxf(red[tid], red[tid + s]);
    __syncthreads();
  }
  const float gmax = red[0] * cscale;
  __syncthreads();
  float lsum = 0.f;
#pragma unroll
  for (int q = 0; q < 4; ++q) {
    float w = __expf(bufA[tid + q * 1024].x * cscale - gmax);
    bufA[tid + q * 1024].x = w;
    lsum += w;
  }
  red[tid] = lsum;
  __syncthreads();
  for (int s = 512; s > 0; s >>= 1) {
    if (tid < s) red[tid] += red[tid + s];
    __syncthreads();
  }
  const float inv = 1.0f / red[0];
  __syncthreads();

  const int d = tid & 63, g = tid >> 6;
  const unsigned short* vb = Vb + (size_t)b * L_ * E_ + h * D_ + d;
  float acc = 0.f;
  for (int l = g; l < L_; l += 16)
    acc = fmaf(bufA[l].x, bf2f(vb[(size_t)l * E_]), acc);
  red[tid] = acc;
  __syncthreads();
  if (tid < 64) {
    float t = 0.f;
#pragma unroll
    for (int g2 = 0; g2 < 16; ++g2) t += red[g2 * 64 + tid];
    out_flat[b * E_ + tid * H_ + h] = t * inv;
  }
}

// ---------------------------------------------------------------------------
// Kernel 3: y[b,o] = bo[o] + sum_j flat[b,j] * Wo[o,j]  (128 blocks)
// ---------------------------------------------------------------------------
__global__ __launch_bounds__(256) void final_proj(
    const float* __restrict__ flat, const float* __restrict__ Wo,
    const float* __restrict__ bo, float* __restrict__ y) {
  __shared__ float sf[E_];
  const int b = blockIdx.y;
  const int o0 = blockIdx.x * 64;
  for (int j = threadIdx.x; j < E_; j += 256) sf[j] = flat[b * E_ + j];
  __syncthreads();
  const int oo = threadIdx.x >> 2, part = threadIdx.x & 3;
  const int o = o0 + oo;
  const float4* wr = (const float4*)(Wo + (size_t)o * E_) + part * 64;
  const float4* fr = (const float4*)sf + part * 64;
  float s = 0.f;
#pragma unroll 8
  for (int i = 0; i < 64; ++i) {
    float4 w = wr[i];
    float4 f = fr[i];
    s += w.x * f.x + w.y * f.y + w.z * f.z + w.w * f.w;
  }
  s += __shfl_xor(s, 1);
  s += __shfl_xor(s, 2);
  if (part == 0) y[b * E_ + o] = s + bo[o];
}

// ---------------------------------------------------------------------------
// Kernel 4: broadcast y (B,E) to out (B,L,E).
// ---------------------------------------------------------------------------
__global__ void broadcast_out(const float* __restrict__ y,
                              float4* __restrict__ out4) {
  const size_t total = (size_t)B_ * L_ * (E_ / 4);
  const float4* y4 = (const float4*)y;
  for (size_t i = (size_t)blockIdx.x * blockDim.x + threadIdx.x; i < total;
       i += (size_t)gridDim.x * blockDim.x) {
    size_t e4 = i & (E_ / 4 - 1);
    size_t b = i >> 20;
    out4[i] = y4[b * (E_ / 4) + e4];
  }
}

// ---------------------------------------------------------------------------
extern "C" void kernel_launch(void* const* d_in, const int* in_sizes, int n_in,
                              void* d_out, int out_size, void* d_ws,
                              size_t ws_size, hipStream_t stream) {
  const float* x  = (const float*)d_in[0];
  const float* Wq = (const float*)d_in[1];
  const float* bq = (const float*)d_in[2];
  const float* Wk = (const float*)d_in[3];
  const float* bk = (const float*)d_in[4];
  const float* Wv = (const float*)d_in[5];
  const float* bv = (const float*)d_in[6];
  const float* Wo = (const float*)d_in[7];
  const float* bo = (const float*)d_in[8];

  char* w = (char*)d_ws;
  unsigned short* KTb  = (unsigned short*)w;
  unsigned short* Vb   = (unsigned short*)(w + 67108864);
  unsigned short* Wb   = (unsigned short*)(w + 134217728);
  float2* Spart        = (float2*)(w + 140509184);
  float* flat          = (float*)(w + 157286400);
  float* y             = (float*)(w + 157319168);
  unsigned short* QTb  = (unsigned short*)d_out;
  unsigned short* xb   = (unsigned short*)((char*)d_out + 67108864);

  conv_w<<<dim3(1024, 3), 256, 0, stream>>>(Wq, Wk, Wv, Wb);
  conv_x<<<dim3(2048), 256, 0, stream>>>(x, xb);
  qkv_gemm8<<<dim3(12, 128), 512, 0, stream>>>(xb, Wb, bq, bk, bv, QTb, KTb,
                                               Vb);
  corr_fft<<<dim3(B_ * H_, 8), 256, 0, stream>>>(QTb, KTb, Spart);
  corr_post<<<dim3(B_ * H_), 1024, 0, stream>>>(Spart, Vb, flat);
  final_proj<<<dim3(16, B_), 256, 0, stream>>>(flat, Wo, bo, y);
  broadcast_out<<<dim3(2048), 256, 0, stream>>>(y, (float4*)d_out);
}

// Round 10
// 507.913 us; speedup vs baseline: 1.1246x; 1.1246x over previous
//
#include <hip/hip_runtime.h>
#include <hip/hip_bf16.h>
#include <math.h>

// Problem constants (AutoCorrelationAttention): B=8, L=4096, E=1024, H=16, D=64
#define B_ 8
#define L_ 4096
#define E_ 1024
#define H_ 16
#define D_ 64

typedef short short8 __attribute__((ext_vector_type(8)));
typedef float f32x4 __attribute__((ext_vector_type(4)));

__device__ __forceinline__ unsigned short f2bf(float f) {
  unsigned int u = __float_as_uint(f);
  unsigned int r = u + 0x7FFFu + ((u >> 16) & 1u);
  return (unsigned short)(r >> 16);
}
__device__ __forceinline__ float bf2f(unsigned short h) {
  return __uint_as_float(((unsigned int)h) << 16);
}

#define GLDS16(g, l)                                                     \
  __builtin_amdgcn_global_load_lds(                                      \
      (const __attribute__((address_space(1))) void*)(g),                \
      (__attribute__((address_space(3))) void*)(l), 16, 0, 0)

// ---------------------------------------------------------------------------
// Kernel 0a: convert Wq/Wk/Wv to bf16 (rounded), fused [3072][1024] layout.
// ---------------------------------------------------------------------------
__global__ __launch_bounds__(256) void conv_w(
    const float* __restrict__ Wq, const float* __restrict__ Wk,
    const float* __restrict__ Wv, unsigned short* __restrict__ Wb) {
  const int wsel = blockIdx.y;
  const float* W = (wsel == 0) ? Wq : (wsel == 1) ? Wk : Wv;
  size_t i = ((size_t)blockIdx.x * 256 + threadIdx.x) * 4;
  float4 f = *(const float4*)(W + i);
  size_t o = (size_t)wsel * (1024 * 1024) + i;
  *(ushort4*)(Wb + o) =
      make_ushort4(f2bf(f.x), f2bf(f.y), f2bf(f.z), f2bf(f.w));
}

// ---------------------------------------------------------------------------
// Kernel 0b: convert x (fp32) -> xb (bf16, rounded), natural layout.
// ---------------------------------------------------------------------------
__global__ __launch_bounds__(256) void conv_x(const float* __restrict__ x,
                                              unsigned short* __restrict__ xb) {
  const size_t total = (size_t)B_ * L_ * E_ / 8;
  for (size_t i = (size_t)blockIdx.x * blockDim.x + threadIdx.x; i < total;
       i += (size_t)gridDim.x * blockDim.x) {
    float4 a = ((const float4*)x)[i * 2];
    float4 b = ((const float4*)x)[i * 2 + 1];
    short8 v;
    v[0] = (short)f2bf(a.x); v[1] = (short)f2bf(a.y);
    v[2] = (short)f2bf(a.z); v[3] = (short)f2bf(a.w);
    v[4] = (short)f2bf(b.x); v[5] = (short)f2bf(b.y);
    v[6] = (short)f2bf(b.z); v[7] = (short)f2bf(b.w);
    *(short8*)&xb[i * 8] = v;
  }
}

// ---------------------------------------------------------------------------
// Kernel 1: fused QKV projection — 256x256 bf16 MFMA GEMM, 2-phase/K-tile
// with register-cached fragments (reads 24 b128/tile/wave vs 48 in the
// 4-phase variant — LDS-read-BW was the binding constraint).
//   ph0: read af(mh0)+B(all); stage A1,B1(u+1)->nxt; lgkm0; barrier-fenced
//        32 MFMA (q00,q01); barrier
//   ph1: read af(mh1);        stage A0,B0(u+2)->cur; lgkm0; 32 MFMA (q10,q11)
// Boundary: vmcnt(4) (last tile 0) + barrier. T2 swizzle as before.
// Race safety: all reads of a cur-half complete (lgkm0 + ph0 barrier) before
// any wave's ph1 stage writes the disjoint half0s.
// ---------------------------------------------------------------------------
#define STAGE_A(buf, h, s, t)                                                \
  GLDS16(xb + (size_t)(m0 + (s)*128 + (h)*64 + srow) * E_ + (t)*64 + scol,   \
         &sA[buf][((s)*128 + (h)*64 + wid * 8) * 64])
#define STAGE_B(buf, h, s, t)                                                \
  GLDS16(Wb + (size_t)(n0 + (s)*128 + (h)*32 + brow_i) * E_ + (t)*64 + scol, \
         &sB[buf][((s)*128 + (h)*32 + bw) * 64])

__global__ __launch_bounds__(512) void qkv_gemm8(
    const unsigned short* __restrict__ xb,
    const unsigned short* __restrict__ Wb, const float* __restrict__ bq,
    const float* __restrict__ bk, const float* __restrict__ bv,
    unsigned short* __restrict__ QTb, unsigned short* __restrict__ KTb,
    unsigned short* __restrict__ Vb) {
  __shared__ unsigned short sA[2][256 * 64];  // 2 x 32 KB
  __shared__ unsigned short sB[2][256 * 64];  // 2 x 32 KB

  const int tid = threadIdx.x;
  const int wid = tid >> 6, lane = tid & 63;
  const int wr = wid >> 2, wc = wid & 3;
  const int fr = lane & 15, fg = lane >> 4, fr7 = fr & 7;
  const int n0 = blockIdx.x * 256;
  const int m0 = blockIdx.y * 256;

  const int srow = tid >> 3;
  const int scol = ((tid & 7) ^ (srow & 7)) * 8;
  const int brow_i = ((srow >> 5) << 6) + (srow & 31);
  const int bw = ((wid >> 2) << 6) + ((wid & 3) << 3);

  f32x4 acc[8][4];
#pragma unroll
  for (int i = 0; i < 8; ++i)
#pragma unroll
    for (int j = 0; j < 4; ++j) acc[i][j] = (f32x4){0.f, 0.f, 0.f, 0.f};

  // prologue: tile0 full -> buf0 (8 ops), tile1 half0s -> buf1 (4 ops)
  STAGE_A(0, 0, 0, 0); STAGE_A(0, 0, 1, 0);
  STAGE_A(0, 1, 0, 0); STAGE_A(0, 1, 1, 0);
  STAGE_B(0, 0, 0, 0); STAGE_B(0, 0, 1, 0);
  STAGE_B(0, 1, 0, 0); STAGE_B(0, 1, 1, 0);
  STAGE_A(1, 0, 0, 1); STAGE_A(1, 0, 1, 1);
  STAGE_B(1, 0, 0, 1); STAGE_B(1, 0, 1, 1);

  const int NT = E_ / 64;  // 16 K-tiles
  for (int u = 0; u < NT; ++u) {
    const int cur = u & 1, nxt = cur ^ 1;
    __builtin_amdgcn_sched_barrier(0);
    if (u == NT - 1)
      asm volatile("s_waitcnt vmcnt(0)" ::: "memory");
    else
      asm volatile("s_waitcnt vmcnt(4)" ::: "memory");
    __builtin_amdgcn_sched_barrier(0);
    __builtin_amdgcn_s_barrier();

    // ---- ph0: af(mh0) + all B fragments
    short8 af[4][2], b0[2][2], b1[2][2];
#pragma unroll
    for (int i = 0; i < 4; ++i)
#pragma unroll
      for (int kk = 0; kk < 2; ++kk) {
        const int blk = (((kk * 4 + fg) ^ fr7) << 3);
        af[i][kk] = *(const short8*)
            &sA[cur][(wr * 128 + i * 16 + fr) * 64 + blk];
      }
#pragma unroll
    for (int j = 0; j < 2; ++j)
#pragma unroll
      for (int kk = 0; kk < 2; ++kk) {
        const int blk = (((kk * 4 + fg) ^ fr7) << 3);
        b0[j][kk] = *(const short8*)
            &sB[cur][(wc * 64 + j * 16 + fr) * 64 + blk];
        b1[j][kk] = *(const short8*)
            &sB[cur][(wc * 64 + (2 + j) * 16 + fr) * 64 + blk];
      }
    if (u + 1 < NT) {
      STAGE_A(nxt, 1, 0, u + 1); STAGE_A(nxt, 1, 1, u + 1);
      STAGE_B(nxt, 1, 0, u + 1); STAGE_B(nxt, 1, 1, u + 1);
    }
    asm volatile("s_waitcnt lgkmcnt(0)" ::: "memory");
    __builtin_amdgcn_sched_barrier(0);
    __builtin_amdgcn_s_setprio(1);
#pragma unroll
    for (int i = 0; i < 4; ++i)
#pragma unroll
      for (int kk = 0; kk < 2; ++kk) {
        acc[i][0] = __builtin_amdgcn_mfma_f32_16x16x32_bf16(af[i][kk], b0[0][kk], acc[i][0], 0, 0, 0);
        acc[i][1] = __builtin_amdgcn_mfma_f32_16x16x32_bf16(af[i][kk], b0[1][kk], acc[i][1], 0, 0, 0);
        acc[i][2] = __builtin_amdgcn_mfma_f32_16x16x32_bf16(af[i][kk], b1[0][kk], acc[i][2], 0, 0, 0);
        acc[i][3] = __builtin_amdgcn_mfma_f32_16x16x32_bf16(af[i][kk], b1[1][kk], acc[i][3], 0, 0, 0);
      }
    __builtin_amdgcn_s_setprio(0);
    __builtin_amdgcn_s_barrier();

    // ---- ph1: af(mh1) only (B cached in regs)
#pragma unroll
    for (int i = 0; i < 4; ++i)
#pragma unroll
      for (int kk = 0; kk < 2; ++kk) {
        const int blk = (((kk * 4 + fg) ^ fr7) << 3);
        af[i][kk] = *(const short8*)
            &sA[cur][(wr * 128 + 64 + i * 16 + fr) * 64 + blk];
      }
    if (u + 2 < NT) {
      STAGE_A(cur, 0, 0, u + 2); STAGE_A(cur, 0, 1, u + 2);
      STAGE_B(cur, 0, 0, u + 2); STAGE_B(cur, 0, 1, u + 2);
    }
    asm volatile("s_waitcnt lgkmcnt(0)" ::: "memory");
    __builtin_amdgcn_sched_barrier(0);
    __builtin_amdgcn_s_setprio(1);
#pragma unroll
    for (int i = 0; i < 4; ++i)
#pragma unroll
      for (int kk = 0; kk < 2; ++kk) {
        acc[4 + i][0] = __builtin_amdgcn_mfma_f32_16x16x32_bf16(af[i][kk], b0[0][kk], acc[4 + i][0], 0, 0, 0);
        acc[4 + i][1] = __builtin_amdgcn_mfma_f32_16x16x32_bf16(af[i][kk], b0[1][kk], acc[4 + i][1], 0, 0, 0);
        acc[4 + i][2] = __builtin_amdgcn_mfma_f32_16x16x32_bf16(af[i][kk], b1[0][kk], acc[4 + i][2], 0, 0, 0);
        acc[4 + i][3] = __builtin_amdgcn_mfma_f32_16x16x32_bf16(af[i][kk], b1[1][kk], acc[4 + i][3], 0, 0, 0);
      }
    __builtin_amdgcn_s_setprio(0);
  }

  // ---- epilogue
  const int wsel = n0 >> 10;
  const float* bias = (wsel == 0) ? bq : (wsel == 1) ? bk : bv;
  float br[4];
#pragma unroll
  for (int j = 0; j < 4; ++j)
    br[j] = bias[(n0 & 1023) + wc * 64 + j * 16 + fr];

  if (wsel < 2) {
    unsigned short* T = (wsel == 0) ? QTb : KTb;
    const int b = m0 >> 12;
    const int lbase = (m0 & 4095) + wr * 128 + (fg << 2);
#pragma unroll
    for (int i = 0; i < 8; ++i)
#pragma unroll
      for (int j = 0; j < 4; ++j) {
        const int n_in = (n0 & 1023) + wc * 64 + j * 16 + fr;
        ushort4 v = make_ushort4(f2bf(acc[i][j][0] + br[j]),
                                 f2bf(acc[i][j][1] + br[j]),
                                 f2bf(acc[i][j][2] + br[j]),
                                 f2bf(acc[i][j][3] + br[j]));
        *(ushort4*)&T[((size_t)(b << 10) + n_in) * L_ + lbase + i * 16] = v;
      }
  } else {
#pragma unroll
    for (int i = 0; i < 8; ++i)
#pragma unroll
      for (int j = 0; j < 4; ++j) {
        const int n_in = (n0 & 1023) + wc * 64 + j * 16 + fr;
#pragma unroll
        for (int r = 0; r < 4; ++r) {
          const int m = m0 + wr * 128 + i * 16 + (fg << 2) + r;
          Vb[(size_t)m * E_ + n_in] = f2bf(acc[i][j][r] + br[j]);
        }
      }
  }
}

// ---------------------------------------------------------------------------
// Radix-4 Stockham FFT, N=4096, 1024 threads, 6 stages, twiddles hoisted.
// (R8 version — measured-best for corr_fft/corr_post.)
// ---------------------------------------------------------------------------
__device__ __forceinline__ float2 cmulf(float2 a, float2 b) {
  return make_float2(a.x * b.x - a.y * b.y, a.x * b.y + a.y * b.x);
}

__device__ __forceinline__ void fft_tw_init(float2* tw, int tid, float sign) {
  const float TWO_PI = 6.28318530717958647692f;
#pragma unroll
  for (int st = 0; st < 6; ++st) {
    const int Ns = 1 << (2 * st);
    const int r = tid & (Ns - 1);
    float ang = sign * TWO_PI * (float)r / (float)(4 * Ns);
    __sincosf(ang, &tw[st].y, &tw[st].x);
  }
}

__device__ __forceinline__ void fft4096_tw(float2* __restrict__ A,
                                           float2* __restrict__ Bb, int tid,
                                           float sign,
                                           const float2* __restrict__ tw) {
  float2* cur = A;
  float2* nxt = Bb;
#pragma unroll
  for (int st = 0; st < 6; ++st) {
    const int Ns = 1 << (2 * st);
    __syncthreads();
    const int j = tid;
    float2 v0 = cur[j];
    float2 v1 = cur[j + 1024];
    float2 v2 = cur[j + 2048];
    float2 v3 = cur[j + 3072];
    const int r = j & (Ns - 1);
    if (st > 0) {
      float2 w1 = tw[st];
      float2 w2 = cmulf(w1, w1);
      float2 w3 = cmulf(w2, w1);
      v1 = cmulf(v1, w1);
      v2 = cmulf(v2, w2);
      v3 = cmulf(v3, w3);
    }
    float2 t0 = make_float2(v0.x + v2.x, v0.y + v2.y);
    float2 t1 = make_float2(v0.x - v2.x, v0.y - v2.y);
    float2 t2 = make_float2(v1.x + v3.x, v1.y + v3.y);
    float2 t3 = make_float2(v1.x - v3.x, v1.y - v3.y);
    float2 t3i = make_float2(-sign * t3.y, sign * t3.x);
    const int idxD = ((j - r) << 2) + r;
    nxt[idxD]          = make_float2(t0.x + t2.x, t0.y + t2.y);
    nxt[idxD + Ns]     = make_float2(t1.x + t3i.x, t1.y + t3i.y);
    nxt[idxD + 2 * Ns] = make_float2(t0.x - t2.x, t0.y - t2.y);
    nxt[idxD + 3 * Ns] = make_float2(t1.x - t3i.x, t1.y - t3i.y);
    float2* tmp = cur; cur = nxt; nxt = tmp;
  }
  __syncthreads();
}

// ---------------------------------------------------------------------------
// Kernel 2a: per-(b,h,ds) partial cross-spectrum. 8 packed FFTs per block.
// ---------------------------------------------------------------------------
__global__ __launch_bounds__(1024) void corr_fft(
    const unsigned short* __restrict__ QTb,
    const unsigned short* __restrict__ KTb, float2* __restrict__ Spart) {
  __shared__ float2 bufA[L_];      // 32 KB
  __shared__ float2 bufB[L_];      // 32 KB
  __shared__ float2 S[L_ / 2];     // 16 KB (Nyquist packed into S[0].y)

  const int bh = blockIdx.x, ds = blockIdx.y;
  const int b = bh >> 4, h = bh & (H_ - 1);
  const int tid = threadIdx.x;

  float2 tw[6];
  fft_tw_init(tw, tid, -1.0f);

  for (int f = tid; f < L_ / 2; f += 1024) S[f] = make_float2(0.f, 0.f);

  const size_t baseQK = (size_t)(b * E_ + h * D_) * L_;

  for (int dd = 0; dd < 8; ++dd) {
    const int d = ds * 8 + dd;
    __syncthreads();
    const unsigned short* q = QTb + baseQK + (size_t)d * L_;
    const unsigned short* k = KTb + baseQK + (size_t)d * L_;
    ushort4 q4 = *(const ushort4*)(q + tid * 4);
    ushort4 k4 = *(const ushort4*)(k + tid * 4);
    bufA[tid * 4 + 0] = make_float2(bf2f(q4.x), bf2f(k4.x));
    bufA[tid * 4 + 1] = make_float2(bf2f(q4.y), bf2f(k4.y));
    bufA[tid * 4 + 2] = make_float2(bf2f(q4.z), bf2f(k4.z));
    bufA[tid * 4 + 3] = make_float2(bf2f(q4.w), bf2f(k4.w));
    fft4096_tw(bufA, bufB, tid, -1.0f, tw);
    for (int f = tid; f <= L_ / 2; f += 1024) {
      float2 Zf = bufA[f];
      float2 Zc = bufA[(L_ - f) & (L_ - 1)];
      float ax = Zc.x, ay = -Zc.y;
      float qx = 0.5f * (Zf.x + ax), qy = 0.5f * (Zf.y + ay);
      float ux = Zf.x - ax, uy = Zf.y - ay;
      float kx = 0.5f * uy, ky = -0.5f * ux;
      float re = qx * kx + qy * ky;
      float im = qy * kx - qx * ky;
      if (f == 0) S[0].x += re;
      else if (f == L_ / 2) S[0].y += re;
      else { S[f].x += re; S[f].y += im; }
    }
  }
  __syncthreads();
  float2* out = Spart + (size_t)(bh * 8 + ds) * (L_ / 2);
  for (int f = tid; f < L_ / 2; f += 1024) out[f] = S[f];
}

// ---------------------------------------------------------------------------
// Kernel 2b: per-(b,h) reduce partials -> inverse FFT -> softmax -> attn@V.
// ---------------------------------------------------------------------------
__global__ __launch_bounds__(1024) void corr_post(
    const float2* __restrict__ Spart, const unsigned short* __restrict__ Vb,
    float* __restrict__ out_flat) {
  __shared__ float2 bufA[L_];
  __shared__ float2 bufB[L_];
  __shared__ float red[1024];

  const int bh = blockIdx.x;
  const int b = bh >> 4, h = bh & (H_ - 1);
  const int tid = threadIdx.x;

  float2 tw[6];
  fft_tw_init(tw, tid, 1.0f);

  const float2* sp = Spart + (size_t)(bh * 8) * (L_ / 2);
  for (int f = tid; f < L_ / 2; f += 1024) {
    float2 s = make_float2(0.f, 0.f);
#pragma unroll
    for (int ds = 0; ds < 8; ++ds) {
      float2 p = sp[(size_t)ds * (L_ / 2) + f];
      s.x += p.x;
      s.y += p.y;
    }
    if (f == 0) {
      bufA[0] = make_float2(s.x, 0.f);
      bufA[L_ / 2] = make_float2(s.y, 0.f);
    } else {
      bufA[f] = s;
      bufA[L_ - f] = make_float2(s.x, -s.y);
    }
  }
  fft4096_tw(bufA, bufB, tid, 1.0f, tw);

  const float cscale = 1.0f / ((float)L_ * (float)D_);
  float lmax = -3.0e38f;
#pragma unroll
  for (int q = 0; q < 4; ++q) lmax = fmaxf(lmax, bufA[tid + q * 1024].x);
  red[tid] = lmax;
  __syncthreads();
  for (int s = 512; s > 0; s >>= 1) {
    if (tid < s) red[tid] = fmaxf(red[tid], red[tid + s]);
    __syncthreads();
  }
  const float gmax = red[0] * cscale;
  __syncthreads();
  float lsum = 0.f;
#pragma unroll
  for (int q = 0; q < 4; ++q) {
    float w = __expf(bufA[tid + q * 1024].x * cscale - gmax);
    bufA[tid + q * 1024].x = w;
    lsum += w;
  }
  red[tid] = lsum;
  __syncthreads();
  for (int s = 512; s > 0; s >>= 1) {
    if (tid < s) red[tid] += red[tid + s];
    __syncthreads();
  }
  const float inv = 1.0f / red[0];
  __syncthreads();

  const int d = tid & 63, g = tid >> 6;
  const unsigned short* vb = Vb + (size_t)b * L_ * E_ + h * D_ + d;
  float acc = 0.f;
  for (int l = g; l < L_; l += 16)
    acc = fmaf(bufA[l].x, bf2f(vb[(size_t)l * E_]), acc);
  red[tid] = acc;
  __syncthreads();
  if (tid < 64) {
    float t = 0.f;
#pragma unroll
    for (int g2 = 0; g2 < 16; ++g2) t += red[g2 * 64 + tid];
    out_flat[b * E_ + tid * H_ + h] = t * inv;
  }
}

// ---------------------------------------------------------------------------
// Kernel 3: y[b,o] = bo[o] + sum_j flat[b,j] * Wo[o,j]  (128 blocks)
// ---------------------------------------------------------------------------
__global__ __launch_bounds__(256) void final_proj(
    const float* __restrict__ flat, const float* __restrict__ Wo,
    const float* __restrict__ bo, float* __restrict__ y) {
  __shared__ float sf[E_];
  const int b = blockIdx.y;
  const int o0 = blockIdx.x * 64;
  for (int j = threadIdx.x; j < E_; j += 256) sf[j] = flat[b * E_ + j];
  __syncthreads();
  const int oo = threadIdx.x >> 2, part = threadIdx.x & 3;
  const int o = o0 + oo;
  const float4* wr = (const float4*)(Wo + (size_t)o * E_) + part * 64;
  const float4* fr = (const float4*)sf + part * 64;
  float s = 0.f;
#pragma unroll 8
  for (int i = 0; i < 64; ++i) {
    float4 w = wr[i];
    float4 f = fr[i];
    s += w.x * f.x + w.y * f.y + w.z * f.z + w.w * f.w;
  }
  s += __shfl_xor(s, 1);
  s += __shfl_xor(s, 2);
  if (part == 0) y[b * E_ + o] = s + bo[o];
}

// ---------------------------------------------------------------------------
// Kernel 4: broadcast y (B,E) to out (B,L,E).
// ---------------------------------------------------------------------------
__global__ void broadcast_out(const float* __restrict__ y,
                              float4* __restrict__ out4) {
  const size_t total = (size_t)B_ * L_ * (E_ / 4);
  const float4* y4 = (const float4*)y;
  for (size_t i = (size_t)blockIdx.x * blockDim.x + threadIdx.x; i < total;
       i += (size_t)gridDim.x * blockDim.x) {
    size_t e4 = i & (E_ / 4 - 1);
    size_t b = i >> 20;
    out4[i] = y4[b * (E_ / 4) + e4];
  }
}

// ---------------------------------------------------------------------------
extern "C" void kernel_launch(void* const* d_in, const int* in_sizes, int n_in,
                              void* d_out, int out_size, void* d_ws,
                              size_t ws_size, hipStream_t stream) {
  const float* x  = (const float*)d_in[0];
  const float* Wq = (const float*)d_in[1];
  const float* bq = (const float*)d_in[2];
  const float* Wk = (const float*)d_in[3];
  const float* bk = (const float*)d_in[4];
  const float* Wv = (const float*)d_in[5];
  const float* bv = (const float*)d_in[6];
  const float* Wo = (const float*)d_in[7];
  const float* bo = (const float*)d_in[8];

  char* w = (char*)d_ws;
  unsigned short* KTb  = (unsigned short*)w;
  unsigned short* Vb   = (unsigned short*)(w + 67108864);
  unsigned short* Wb   = (unsigned short*)(w + 134217728);
  float2* Spart        = (float2*)(w + 140509184);
  float* flat          = (float*)(w + 157286400);
  float* y             = (float*)(w + 157319168);
  unsigned short* QTb  = (unsigned short*)d_out;
  unsigned short* xb   = (unsigned short*)((char*)d_out + 67108864);

  conv_w<<<dim3(1024, 3), 256, 0, stream>>>(Wq, Wk, Wv, Wb);
  conv_x<<<dim3(2048), 256, 0, stream>>>(x, xb);
  qkv_gemm8<<<dim3(12, 128), 512, 0, stream>>>(xb, Wb, bq, bk, bv, QTb, KTb,
                                               Vb);
  corr_fft<<<dim3(B_ * H_, 8), 1024, 0, stream>>>(QTb, KTb, Spart);
  corr_post<<<dim3(B_ * H_), 1024, 0, stream>>>(Spart, Vb, flat);
  final_proj<<<dim3(16, B_), 256, 0, stream>>>(flat, Wo, bo, y);
  broadcast_out<<<dim3(2048), 256, 0, stream>>>(y, (float4*)d_out);
}

// Round 11
// 486.861 us; speedup vs baseline: 1.1732x; 1.0432x over previous
//
#include <hip/hip_runtime.h>
#include <hip/hip_bf16.h>
#include <math.h>

// Problem constants (AutoCorrelationAttention): B=8, L=4096, E=1024, H=16, D=64
#define B_ 8
#define L_ 4096
#define E_ 1024
#define H_ 16
#define D_ 64

typedef short short8 __attribute__((ext_vector_type(8)));
typedef float f32x4 __attribute__((ext_vector_type(4)));

__device__ __forceinline__ unsigned short f2bf(float f) {
  unsigned int u = __float_as_uint(f);
  unsigned int r = u + 0x7FFFu + ((u >> 16) & 1u);
  return (unsigned short)(r >> 16);
}
__device__ __forceinline__ float bf2f(unsigned short h) {
  return __uint_as_float(((unsigned int)h) << 16);
}

#define GLDS16(g, l)                                                     \
  __builtin_amdgcn_global_load_lds(                                      \
      (const __attribute__((address_space(1))) void*)(g),                \
      (__attribute__((address_space(3))) void*)(l), 16, 0, 0)

// ---------------------------------------------------------------------------
// Kernel 0a: convert Wq/Wk/Wv to bf16 (rounded), fused [3072][1024] layout.
// ---------------------------------------------------------------------------
__global__ __launch_bounds__(256) void conv_w(
    const float* __restrict__ Wq, const float* __restrict__ Wk,
    const float* __restrict__ Wv, unsigned short* __restrict__ Wb) {
  const int wsel = blockIdx.y;
  const float* W = (wsel == 0) ? Wq : (wsel == 1) ? Wk : Wv;
  size_t i = ((size_t)blockIdx.x * 256 + threadIdx.x) * 4;
  float4 f = *(const float4*)(W + i);
  size_t o = (size_t)wsel * (1024 * 1024) + i;
  *(ushort4*)(Wb + o) =
      make_ushort4(f2bf(f.x), f2bf(f.y), f2bf(f.z), f2bf(f.w));
}

// ---------------------------------------------------------------------------
// Kernel 0b: convert x (fp32) -> xb (bf16, rounded), natural layout.
// ---------------------------------------------------------------------------
__global__ __launch_bounds__(256) void conv_x(const float* __restrict__ x,
                                              unsigned short* __restrict__ xb) {
  const size_t total = (size_t)B_ * L_ * E_ / 8;
  for (size_t i = (size_t)blockIdx.x * blockDim.x + threadIdx.x; i < total;
       i += (size_t)gridDim.x * blockDim.x) {
    float4 a = ((const float4*)x)[i * 2];
    float4 b = ((const float4*)x)[i * 2 + 1];
    short8 v;
    v[0] = (short)f2bf(a.x); v[1] = (short)f2bf(a.y);
    v[2] = (short)f2bf(a.z); v[3] = (short)f2bf(a.w);
    v[4] = (short)f2bf(b.x); v[5] = (short)f2bf(b.y);
    v[6] = (short)f2bf(b.z); v[7] = (short)f2bf(b.w);
    *(short8*)&xb[i * 8] = v;
  }
}

// ---------------------------------------------------------------------------
// Kernel 1: fused QKV projection — 256x256 bf16 MFMA GEMM, 2-phase/K-tile
// with register-cached fragments. (unchanged from R10 — 212 us, MfmaUtil 43%)
// ---------------------------------------------------------------------------
#define STAGE_A(buf, h, s, t)                                                \
  GLDS16(xb + (size_t)(m0 + (s)*128 + (h)*64 + srow) * E_ + (t)*64 + scol,   \
         &sA[buf][((s)*128 + (h)*64 + wid * 8) * 64])
#define STAGE_B(buf, h, s, t)                                                \
  GLDS16(Wb + (size_t)(n0 + (s)*128 + (h)*32 + brow_i) * E_ + (t)*64 + scol, \
         &sB[buf][((s)*128 + (h)*32 + bw) * 64])

__global__ __launch_bounds__(512) void qkv_gemm8(
    const unsigned short* __restrict__ xb,
    const unsigned short* __restrict__ Wb, const float* __restrict__ bq,
    const float* __restrict__ bk, const float* __restrict__ bv,
    unsigned short* __restrict__ QTb, unsigned short* __restrict__ KTb,
    unsigned short* __restrict__ Vb) {
  __shared__ unsigned short sA[2][256 * 64];  // 2 x 32 KB
  __shared__ unsigned short sB[2][256 * 64];  // 2 x 32 KB

  const int tid = threadIdx.x;
  const int wid = tid >> 6, lane = tid & 63;
  const int wr = wid >> 2, wc = wid & 3;
  const int fr = lane & 15, fg = lane >> 4, fr7 = fr & 7;
  const int n0 = blockIdx.x * 256;
  const int m0 = blockIdx.y * 256;

  const int srow = tid >> 3;
  const int scol = ((tid & 7) ^ (srow & 7)) * 8;
  const int brow_i = ((srow >> 5) << 6) + (srow & 31);
  const int bw = ((wid >> 2) << 6) + ((wid & 3) << 3);

  f32x4 acc[8][4];
#pragma unroll
  for (int i = 0; i < 8; ++i)
#pragma unroll
    for (int j = 0; j < 4; ++j) acc[i][j] = (f32x4){0.f, 0.f, 0.f, 0.f};

  STAGE_A(0, 0, 0, 0); STAGE_A(0, 0, 1, 0);
  STAGE_A(0, 1, 0, 0); STAGE_A(0, 1, 1, 0);
  STAGE_B(0, 0, 0, 0); STAGE_B(0, 0, 1, 0);
  STAGE_B(0, 1, 0, 0); STAGE_B(0, 1, 1, 0);
  STAGE_A(1, 0, 0, 1); STAGE_A(1, 0, 1, 1);
  STAGE_B(1, 0, 0, 1); STAGE_B(1, 0, 1, 1);

  const int NT = E_ / 64;  // 16 K-tiles
  for (int u = 0; u < NT; ++u) {
    const int cur = u & 1, nxt = cur ^ 1;
    __builtin_amdgcn_sched_barrier(0);
    if (u == NT - 1)
      asm volatile("s_waitcnt vmcnt(0)" ::: "memory");
    else
      asm volatile("s_waitcnt vmcnt(4)" ::: "memory");
    __builtin_amdgcn_sched_barrier(0);
    __builtin_amdgcn_s_barrier();

    short8 af[4][2], b0[2][2], b1[2][2];
#pragma unroll
    for (int i = 0; i < 4; ++i)
#pragma unroll
      for (int kk = 0; kk < 2; ++kk) {
        const int blk = (((kk * 4 + fg) ^ fr7) << 3);
        af[i][kk] = *(const short8*)
            &sA[cur][(wr * 128 + i * 16 + fr) * 64 + blk];
      }
#pragma unroll
    for (int j = 0; j < 2; ++j)
#pragma unroll
      for (int kk = 0; kk < 2; ++kk) {
        const int blk = (((kk * 4 + fg) ^ fr7) << 3);
        b0[j][kk] = *(const short8*)
            &sB[cur][(wc * 64 + j * 16 + fr) * 64 + blk];
        b1[j][kk] = *(const short8*)
            &sB[cur][(wc * 64 + (2 + j) * 16 + fr) * 64 + blk];
      }
    if (u + 1 < NT) {
      STAGE_A(nxt, 1, 0, u + 1); STAGE_A(nxt, 1, 1, u + 1);
      STAGE_B(nxt, 1, 0, u + 1); STAGE_B(nxt, 1, 1, u + 1);
    }
    asm volatile("s_waitcnt lgkmcnt(0)" ::: "memory");
    __builtin_amdgcn_sched_barrier(0);
    __builtin_amdgcn_s_setprio(1);
#pragma unroll
    for (int i = 0; i < 4; ++i)
#pragma unroll
      for (int kk = 0; kk < 2; ++kk) {
        acc[i][0] = __builtin_amdgcn_mfma_f32_16x16x32_bf16(af[i][kk], b0[0][kk], acc[i][0], 0, 0, 0);
        acc[i][1] = __builtin_amdgcn_mfma_f32_16x16x32_bf16(af[i][kk], b0[1][kk], acc[i][1], 0, 0, 0);
        acc[i][2] = __builtin_amdgcn_mfma_f32_16x16x32_bf16(af[i][kk], b1[0][kk], acc[i][2], 0, 0, 0);
        acc[i][3] = __builtin_amdgcn_mfma_f32_16x16x32_bf16(af[i][kk], b1[1][kk], acc[i][3], 0, 0, 0);
      }
    __builtin_amdgcn_s_setprio(0);
    __builtin_amdgcn_s_barrier();

#pragma unroll
    for (int i = 0; i < 4; ++i)
#pragma unroll
      for (int kk = 0; kk < 2; ++kk) {
        const int blk = (((kk * 4 + fg) ^ fr7) << 3);
        af[i][kk] = *(const short8*)
            &sA[cur][(wr * 128 + 64 + i * 16 + fr) * 64 + blk];
      }
    if (u + 2 < NT) {
      STAGE_A(cur, 0, 0, u + 2); STAGE_A(cur, 0, 1, u + 2);
      STAGE_B(cur, 0, 0, u + 2); STAGE_B(cur, 0, 1, u + 2);
    }
    asm volatile("s_waitcnt lgkmcnt(0)" ::: "memory");
    __builtin_amdgcn_sched_barrier(0);
    __builtin_amdgcn_s_setprio(1);
#pragma unroll
    for (int i = 0; i < 4; ++i)
#pragma unroll
      for (int kk = 0; kk < 2; ++kk) {
        acc[4 + i][0] = __builtin_amdgcn_mfma_f32_16x16x32_bf16(af[i][kk], b0[0][kk], acc[4 + i][0], 0, 0, 0);
        acc[4 + i][1] = __builtin_amdgcn_mfma_f32_16x16x32_bf16(af[i][kk], b0[1][kk], acc[4 + i][1], 0, 0, 0);
        acc[4 + i][2] = __builtin_amdgcn_mfma_f32_16x16x32_bf16(af[i][kk], b1[0][kk], acc[4 + i][2], 0, 0, 0);
        acc[4 + i][3] = __builtin_amdgcn_mfma_f32_16x16x32_bf16(af[i][kk], b1[1][kk], acc[4 + i][3], 0, 0, 0);
      }
    __builtin_amdgcn_s_setprio(0);
  }

  const int wsel = n0 >> 10;
  const float* bias = (wsel == 0) ? bq : (wsel == 1) ? bk : bv;
  float br[4];
#pragma unroll
  for (int j = 0; j < 4; ++j)
    br[j] = bias[(n0 & 1023) + wc * 64 + j * 16 + fr];

  if (wsel < 2) {
    unsigned short* T = (wsel == 0) ? QTb : KTb;
    const int b = m0 >> 12;
    const int lbase = (m0 & 4095) + wr * 128 + (fg << 2);
#pragma unroll
    for (int i = 0; i < 8; ++i)
#pragma unroll
      for (int j = 0; j < 4; ++j) {
        const int n_in = (n0 & 1023) + wc * 64 + j * 16 + fr;
        ushort4 v = make_ushort4(f2bf(acc[i][j][0] + br[j]),
                                 f2bf(acc[i][j][1] + br[j]),
                                 f2bf(acc[i][j][2] + br[j]),
                                 f2bf(acc[i][j][3] + br[j]));
        *(ushort4*)&T[((size_t)(b << 10) + n_in) * L_ + lbase + i * 16] = v;
      }
  } else {
#pragma unroll
    for (int i = 0; i < 8; ++i)
#pragma unroll
      for (int j = 0; j < 4; ++j) {
        const int n_in = (n0 & 1023) + wc * 64 + j * 16 + fr;
#pragma unroll
        for (int r = 0; r < 4; ++r) {
          const int m = m0 + wr * 128 + i * 16 + (fg << 2) + r;
          Vb[(size_t)m * E_ + n_in] = f2bf(acc[i][j][r] + br[j]);
        }
      }
  }
}

// ---------------------------------------------------------------------------
// Complex helpers.
// ---------------------------------------------------------------------------
__device__ __forceinline__ float2 cmulf(float2 a, float2 b) {
  return make_float2(a.x * b.x - a.y * b.y, a.x * b.y + a.y * b.x);
}
// two complex numbers (a.xy, a.zw) times one twiddle w
__device__ __forceinline__ float4 cmul4(float4 a, float2 w) {
  return make_float4(a.x * w.x - a.y * w.y, a.x * w.y + a.y * w.x,
                     a.z * w.x - a.w * w.y, a.z * w.y + a.w * w.x);
}

__device__ __forceinline__ void fft_tw_init(float2* tw, int tid, float sign) {
  const float TWO_PI = 6.28318530717958647692f;
#pragma unroll
  for (int st = 0; st < 6; ++st) {
    const int Ns = 1 << (2 * st);
    const int r = tid & (Ns - 1);
    float ang = sign * TWO_PI * (float)r / (float)(4 * Ns);
    __sincosf(ang, &tw[st].y, &tw[st].x);
  }
}

// ---------------------------------------------------------------------------
// Dual-FFT radix-4 Stockham, N=4096, 1024 threads: two independent packed
// FFTs ride in .xy / .zw of float4 elements. 6 stages, result in A.
// Halves barrier count per FFT vs the float2 version; all LDS ops b128.
// ---------------------------------------------------------------------------
__device__ __forceinline__ void fft4096_tw4(float4* __restrict__ A,
                                            float4* __restrict__ Bb, int tid,
                                            float sign,
                                            const float2* __restrict__ tw) {
  float4* cur = A;
  float4* nxt = Bb;
#pragma unroll
  for (int st = 0; st < 6; ++st) {
    const int Ns = 1 << (2 * st);
    __syncthreads();
    const int j = tid;
    float4 v0 = cur[j];
    float4 v1 = cur[j + 1024];
    float4 v2 = cur[j + 2048];
    float4 v3 = cur[j + 3072];
    const int r = j & (Ns - 1);
    if (st > 0) {
      float2 w1 = tw[st];
      float2 w2 = cmulf(w1, w1);
      float2 w3 = cmulf(w2, w1);
      v1 = cmul4(v1, w1);
      v2 = cmul4(v2, w2);
      v3 = cmul4(v3, w3);
    }
    float4 t0 = make_float4(v0.x + v2.x, v0.y + v2.y, v0.z + v2.z, v0.w + v2.w);
    float4 t1 = make_float4(v0.x - v2.x, v0.y - v2.y, v0.z - v2.z, v0.w - v2.w);
    float4 t2 = make_float4(v1.x + v3.x, v1.y + v3.y, v1.z + v3.z, v1.w + v3.w);
    float4 t3 = make_float4(v1.x - v3.x, v1.y - v3.y, v1.z - v3.z, v1.w - v3.w);
    float4 t3i = make_float4(-sign * t3.y, sign * t3.x, -sign * t3.w, sign * t3.z);
    const int idxD = ((j - r) << 2) + r;
    nxt[idxD] = make_float4(t0.x + t2.x, t0.y + t2.y, t0.z + t2.z, t0.w + t2.w);
    nxt[idxD + Ns] =
        make_float4(t1.x + t3i.x, t1.y + t3i.y, t1.z + t3i.z, t1.w + t3i.w);
    nxt[idxD + 2 * Ns] =
        make_float4(t0.x - t2.x, t0.y - t2.y, t0.z - t2.z, t0.w - t2.w);
    nxt[idxD + 3 * Ns] =
        make_float4(t1.x - t3i.x, t1.y - t3i.y, t1.z - t3i.z, t1.w - t3i.w);
    float4* tmp = cur; cur = nxt; nxt = tmp;
  }
  __syncthreads();
}

// Hermitian split + cross-spectrum for one packed FFT: z = q + i*k.
__device__ __forceinline__ float2 herm(float2 Zf, float2 Zc) {
  float ax = Zc.x, ay = -Zc.y;
  float qx = 0.5f * (Zf.x + ax), qy = 0.5f * (Zf.y + ay);
  float ux = Zf.x - ax, uy = Zf.y - ay;
  float kx = 0.5f * uy, ky = -0.5f * ux;
  return make_float2(qx * kx + qy * ky, qy * kx - qx * ky);
}

// ---------------------------------------------------------------------------
// Kernel 2a: per-(b,h,ds) partial cross-spectrum. 8 FFTs per block as 4
// dual-FFT passes. S accumulator lives in registers (2 float2/thread).
// LDS 128 KB.
// ---------------------------------------------------------------------------
__global__ __launch_bounds__(1024) void corr_fft(
    const unsigned short* __restrict__ QTb,
    const unsigned short* __restrict__ KTb, float2* __restrict__ Spart) {
  __shared__ float4 bufA[L_];      // 64 KB
  __shared__ float4 bufB[L_];      // 64 KB

  const int bh = blockIdx.x, ds = blockIdx.y;
  const int b = bh >> 4, h = bh & (H_ - 1);
  const int tid = threadIdx.x;

  float2 tw[6];
  fft_tw_init(tw, tid, -1.0f);

  float2 s0 = make_float2(0.f, 0.f);  // f = tid  (tid 0: DC in .x, Nyq in .y)
  float2 s1 = make_float2(0.f, 0.f);  // f = tid + 1024

  const size_t baseQK = (size_t)(b * E_ + h * D_) * L_;

  for (int dd = 0; dd < 4; ++dd) {
    const int d0 = ds * 8 + dd * 2;
    __syncthreads();  // prior herm readers of bufA done
    const unsigned short* q0 = QTb + baseQK + (size_t)d0 * L_;
    const unsigned short* k0 = KTb + baseQK + (size_t)d0 * L_;
    ushort4 qa = *(const ushort4*)(q0 + tid * 4);
    ushort4 ka = *(const ushort4*)(k0 + tid * 4);
    ushort4 qb = *(const ushort4*)(q0 + L_ + tid * 4);
    ushort4 kb = *(const ushort4*)(k0 + L_ + tid * 4);
    bufA[tid * 4 + 0] = make_float4(bf2f(qa.x), bf2f(ka.x), bf2f(qb.x), bf2f(kb.x));
    bufA[tid * 4 + 1] = make_float4(bf2f(qa.y), bf2f(ka.y), bf2f(qb.y), bf2f(kb.y));
    bufA[tid * 4 + 2] = make_float4(bf2f(qa.z), bf2f(ka.z), bf2f(qb.z), bf2f(kb.z));
    bufA[tid * 4 + 3] = make_float4(bf2f(qa.w), bf2f(ka.w), bf2f(qb.w), bf2f(kb.w));
    fft4096_tw4(bufA, bufB, tid, -1.0f, tw);
    // f = tid
    {
      float4 Zf = bufA[tid];
      float4 Zc = bufA[(L_ - tid) & (L_ - 1)];
      float2 r0 = herm(make_float2(Zf.x, Zf.y), make_float2(Zc.x, Zc.y));
      float2 r1 = herm(make_float2(Zf.z, Zf.w), make_float2(Zc.z, Zc.w));
      s0.x += r0.x + r1.x;
      s0.y += r0.y + r1.y;  // tid 0: im(DC)=0, so .y stays pure-Nyquist
    }
    if (tid == 0) {  // Nyquist bin f=2048, packed into s0.y
      float4 Zf = bufA[2048];
      float2 r0 = herm(make_float2(Zf.x, Zf.y), make_float2(Zf.x, Zf.y));
      float2 r1 = herm(make_float2(Zf.z, Zf.w), make_float2(Zf.z, Zf.w));
      s0.y += r0.x + r1.x;
    }
    // f = tid + 1024
    {
      float4 Zf = bufA[tid + 1024];
      float4 Zc = bufA[3072 - tid];
      float2 r0 = herm(make_float2(Zf.x, Zf.y), make_float2(Zc.x, Zc.y));
      float2 r1 = herm(make_float2(Zf.z, Zf.w), make_float2(Zc.z, Zc.w));
      s1.x += r0.x + r1.x;
      s1.y += r0.y + r1.y;
    }
  }
  float2* out = Spart + (size_t)(bh * 8 + ds) * (L_ / 2);
  out[tid] = s0;
  out[tid + 1024] = s1;
}

// ---------------------------------------------------------------------------
// Radix-4 Stockham FFT (float2), N=4096, 1024 threads — used by corr_post.
// ---------------------------------------------------------------------------
__device__ __forceinline__ void fft4096_tw(float2* __restrict__ A,
                                           float2* __restrict__ Bb, int tid,
                                           float sign,
                                           const float2* __restrict__ tw) {
  float2* cur = A;
  float2* nxt = Bb;
#pragma unroll
  for (int st = 0; st < 6; ++st) {
    const int Ns = 1 << (2 * st);
    __syncthreads();
    const int j = tid;
    float2 v0 = cur[j];
    float2 v1 = cur[j + 1024];
    float2 v2 = cur[j + 2048];
    float2 v3 = cur[j + 3072];
    const int r = j & (Ns - 1);
    if (st > 0) {
      float2 w1 = tw[st];
      float2 w2 = cmulf(w1, w1);
      float2 w3 = cmulf(w2, w1);
      v1 = cmulf(v1, w1);
      v2 = cmulf(v2, w2);
      v3 = cmulf(v3, w3);
    }
    float2 t0 = make_float2(v0.x + v2.x, v0.y + v2.y);
    float2 t1 = make_float2(v0.x - v2.x, v0.y - v2.y);
    float2 t2 = make_float2(v1.x + v3.x, v1.y + v3.y);
    float2 t3 = make_float2(v1.x - v3.x, v1.y - v3.y);
    float2 t3i = make_float2(-sign * t3.y, sign * t3.x);
    const int idxD = ((j - r) << 2) + r;
    nxt[idxD]          = make_float2(t0.x + t2.x, t0.y + t2.y);
    nxt[idxD + Ns]     = make_float2(t1.x + t3i.x, t1.y + t3i.y);
    nxt[idxD + 2 * Ns] = make_float2(t0.x - t2.x, t0.y - t2.y);
    nxt[idxD + 3 * Ns] = make_float2(t1.x - t3i.x, t1.y - t3i.y);
    float2* tmp = cur; cur = nxt; nxt = tmp;
  }
  __syncthreads();
}

// ---------------------------------------------------------------------------
// Kernel 2b: per-(b,h) reduce partials -> inverse FFT -> softmax -> attn@V.
// ---------------------------------------------------------------------------
__global__ __launch_bounds__(1024) void corr_post(
    const float2* __restrict__ Spart, const unsigned short* __restrict__ Vb,
    float* __restrict__ out_flat) {
  __shared__ float2 bufA[L_];
  __shared__ float2 bufB[L_];
  __shared__ float red[1024];

  const int bh = blockIdx.x;
  const int b = bh >> 4, h = bh & (H_ - 1);
  const int tid = threadIdx.x;

  float2 tw[6];
  fft_tw_init(tw, tid, 1.0f);

  const float2* sp = Spart + (size_t)(bh * 8) * (L_ / 2);
  for (int f = tid; f < L_ / 2; f += 1024) {
    float2 s = make_float2(0.f, 0.f);
#pragma unroll
    for (int ds = 0; ds < 8; ++ds) {
      float2 p = sp[(size_t)ds * (L_ / 2) + f];
      s.x += p.x;
      s.y += p.y;
    }
    if (f == 0) {
      bufA[0] = make_float2(s.x, 0.f);
      bufA[L_ / 2] = make_float2(s.y, 0.f);
    } else {
      bufA[f] = s;
      bufA[L_ - f] = make_float2(s.x, -s.y);
    }
  }
  fft4096_tw(bufA, bufB, tid, 1.0f, tw);

  const float cscale = 1.0f / ((float)L_ * (float)D_);
  float lmax = -3.0e38f;
#pragma unroll
  for (int q = 0; q < 4; ++q) lmax = fmaxf(lmax, bufA[tid + q * 1024].x);
  red[tid] = lmax;
  __syncthreads();
  for (int s = 512; s > 0; s >>= 1) {
    if (tid < s) red[tid] = fmaxf(red[tid], red[tid + s]);
    __syncthreads();
  }
  const float gmax = red[0] * cscale;
  __syncthreads();
  float lsum = 0.f;
#pragma unroll
  for (int q = 0; q < 4; ++q) {
    float w = __expf(bufA[tid + q * 1024].x * cscale - gmax);
    bufA[tid + q * 1024].x = w;
    lsum += w;
  }
  red[tid] = lsum;
  __syncthreads();
  for (int s = 512; s > 0; s >>= 1) {
    if (tid < s) red[tid] += red[tid + s];
    __syncthreads();
  }
  const float inv = 1.0f / red[0];
  __syncthreads();

  const int d = tid & 63, g = tid >> 6;
  const unsigned short* vb = Vb + (size_t)b * L_ * E_ + h * D_ + d;
  float acc = 0.f;
  for (int l = g; l < L_; l += 16)
    acc = fmaf(bufA[l].x, bf2f(vb[(size_t)l * E_]), acc);
  red[tid] = acc;
  __syncthreads();
  if (tid < 64) {
    float t = 0.f;
#pragma unroll
    for (int g2 = 0; g2 < 16; ++g2) t += red[g2 * 64 + tid];
    out_flat[b * E_ + tid * H_ + h] = t * inv;
  }
}

// ---------------------------------------------------------------------------
// Kernel 3: y[b,o] = bo[o] + sum_j flat[b,j] * Wo[o,j]  (128 blocks)
// ---------------------------------------------------------------------------
__global__ __launch_bounds__(256) void final_proj(
    const float* __restrict__ flat, const float* __restrict__ Wo,
    const float* __restrict__ bo, float* __restrict__ y) {
  __shared__ float sf[E_];
  const int b = blockIdx.y;
  const int o0 = blockIdx.x * 64;
  for (int j = threadIdx.x; j < E_; j += 256) sf[j] = flat[b * E_ + j];
  __syncthreads();
  const int oo = threadIdx.x >> 2, part = threadIdx.x & 3;
  const int o = o0 + oo;
  const float4* wr = (const float4*)(Wo + (size_t)o * E_) + part * 64;
  const float4* fr = (const float4*)sf + part * 64;
  float s = 0.f;
#pragma unroll 8
  for (int i = 0; i < 64; ++i) {
    float4 w = wr[i];
    float4 f = fr[i];
    s += w.x * f.x + w.y * f.y + w.z * f.z + w.w * f.w;
  }
  s += __shfl_xor(s, 1);
  s += __shfl_xor(s, 2);
  if (part == 0) y[b * E_ + o] = s + bo[o];
}

// ---------------------------------------------------------------------------
// Kernel 4: broadcast y (B,E) to out (B,L,E).
// ---------------------------------------------------------------------------
__global__ void broadcast_out(const float* __restrict__ y,
                              float4* __restrict__ out4) {
  const size_t total = (size_t)B_ * L_ * (E_ / 4);
  const float4* y4 = (const float4*)y;
  for (size_t i = (size_t)blockIdx.x * blockDim.x + threadIdx.x; i < total;
       i += (size_t)gridDim.x * blockDim.x) {
    size_t e4 = i & (E_ / 4 - 1);
    size_t b = i >> 20;
    out4[i] = y4[b * (E_ / 4) + e4];
  }
}

// ---------------------------------------------------------------------------
extern "C" void kernel_launch(void* const* d_in, const int* in_sizes, int n_in,
                              void* d_out, int out_size, void* d_ws,
                              size_t ws_size, hipStream_t stream) {
  const float* x  = (const float*)d_in[0];
  const float* Wq = (const float*)d_in[1];
  const float* bq = (const float*)d_in[2];
  const float* Wk = (const float*)d_in[3];
  const float* bk = (const float*)d_in[4];
  const float* Wv = (const float*)d_in[5];
  const float* bv = (const float*)d_in[6];
  const float* Wo = (const float*)d_in[7];
  const float* bo = (const float*)d_in[8];

  char* w = (char*)d_ws;
  unsigned short* KTb  = (unsigned short*)w;
  unsigned short* Vb   = (unsigned short*)(w + 67108864);
  unsigned short* Wb   = (unsigned short*)(w + 134217728);
  float2* Spart        = (float2*)(w + 140509184);
  float* flat          = (float*)(w + 157286400);
  float* y             = (float*)(w + 157319168);
  unsigned short* QTb  = (unsigned short*)d_out;
  unsigned short* xb   = (unsigned short*)((char*)d_out + 67108864);

  conv_w<<<dim3(1024, 3), 256, 0, stream>>>(Wq, Wk, Wv, Wb);
  conv_x<<<dim3(2048), 256, 0, stream>>>(x, xb);
  qkv_gemm8<<<dim3(12, 128), 512, 0, stream>>>(xb, Wb, bq, bk, bv, QTb, KTb,
                                               Vb);
  corr_fft<<<dim3(B_ * H_, 8), 1024, 0, stream>>>(QTb, KTb, Spart);
  corr_post<<<dim3(B_ * H_), 1024, 0, stream>>>(Spart, Vb, flat);
  final_proj<<<dim3(16, B_), 256, 0, stream>>>(flat, Wo, bo, y);
  broadcast_out<<<dim3(2048), 256, 0, stream>>>(y, (float4*)d_out);
}

// Round 12
// 466.928 us; speedup vs baseline: 1.2233x; 1.0427x over previous
//
#include <hip/hip_runtime.h>
#include <hip/hip_bf16.h>
#include <math.h>

// Problem constants (AutoCorrelationAttention): B=8, L=4096, E=1024, H=16, D=64
#define B_ 8
#define L_ 4096
#define E_ 1024
#define H_ 16
#define D_ 64

typedef short short8 __attribute__((ext_vector_type(8)));
typedef float f32x4 __attribute__((ext_vector_type(4)));

__device__ __forceinline__ unsigned short f2bf(float f) {
  unsigned int u = __float_as_uint(f);
  unsigned int r = u + 0x7FFFu + ((u >> 16) & 1u);
  return (unsigned short)(r >> 16);
}
__device__ __forceinline__ float bf2f(unsigned short h) {
  return __uint_as_float(((unsigned int)h) << 16);
}

#define GLDS16(g, l)                                                     \
  __builtin_amdgcn_global_load_lds(                                      \
      (const __attribute__((address_space(1))) void*)(g),                \
      (__attribute__((address_space(3))) void*)(l), 16, 0, 0)

// ---------------------------------------------------------------------------
// Kernel 0a: convert Wq/Wk/Wv to bf16 (rounded), fused [3072][1024] layout.
// ---------------------------------------------------------------------------
__global__ __launch_bounds__(256) void conv_w(
    const float* __restrict__ Wq, const float* __restrict__ Wk,
    const float* __restrict__ Wv, unsigned short* __restrict__ Wb) {
  const int wsel = blockIdx.y;
  const float* W = (wsel == 0) ? Wq : (wsel == 1) ? Wk : Wv;
  size_t i = ((size_t)blockIdx.x * 256 + threadIdx.x) * 4;
  float4 f = *(const float4*)(W + i);
  size_t o = (size_t)wsel * (1024 * 1024) + i;
  *(ushort4*)(Wb + o) =
      make_ushort4(f2bf(f.x), f2bf(f.y), f2bf(f.z), f2bf(f.w));
}

// ---------------------------------------------------------------------------
// Kernel 0b: convert x (fp32) -> xb (bf16, rounded), natural layout.
// ---------------------------------------------------------------------------
__global__ __launch_bounds__(256) void conv_x(const float* __restrict__ x,
                                              unsigned short* __restrict__ xb) {
  const size_t total = (size_t)B_ * L_ * E_ / 8;
  for (size_t i = (size_t)blockIdx.x * blockDim.x + threadIdx.x; i < total;
       i += (size_t)gridDim.x * blockDim.x) {
    float4 a = ((const float4*)x)[i * 2];
    float4 b = ((const float4*)x)[i * 2 + 1];
    short8 v;
    v[0] = (short)f2bf(a.x); v[1] = (short)f2bf(a.y);
    v[2] = (short)f2bf(a.z); v[3] = (short)f2bf(a.w);
    v[4] = (short)f2bf(b.x); v[5] = (short)f2bf(b.y);
    v[6] = (short)f2bf(b.z); v[7] = (short)f2bf(b.w);
    *(short8*)&xb[i * 8] = v;
  }
}

// ---------------------------------------------------------------------------
// Kernel 1: fused QKV projection — 256x256 bf16 MFMA GEMM, 2-phase/K-tile
// with register-cached fragments. (unchanged from R10 — 212 us, MfmaUtil 43%)
// ---------------------------------------------------------------------------
#define STAGE_A(buf, h, s, t)                                                \
  GLDS16(xb + (size_t)(m0 + (s)*128 + (h)*64 + srow) * E_ + (t)*64 + scol,   \
         &sA[buf][((s)*128 + (h)*64 + wid * 8) * 64])
#define STAGE_B(buf, h, s, t)                                                \
  GLDS16(Wb + (size_t)(n0 + (s)*128 + (h)*32 + brow_i) * E_ + (t)*64 + scol, \
         &sB[buf][((s)*128 + (h)*32 + bw) * 64])

__global__ __launch_bounds__(512) void qkv_gemm8(
    const unsigned short* __restrict__ xb,
    const unsigned short* __restrict__ Wb, const float* __restrict__ bq,
    const float* __restrict__ bk, const float* __restrict__ bv,
    unsigned short* __restrict__ QTb, unsigned short* __restrict__ KTb,
    unsigned short* __restrict__ Vb) {
  __shared__ unsigned short sA[2][256 * 64];  // 2 x 32 KB
  __shared__ unsigned short sB[2][256 * 64];  // 2 x 32 KB

  const int tid = threadIdx.x;
  const int wid = tid >> 6, lane = tid & 63;
  const int wr = wid >> 2, wc = wid & 3;
  const int fr = lane & 15, fg = lane >> 4, fr7 = fr & 7;
  const int n0 = blockIdx.x * 256;
  const int m0 = blockIdx.y * 256;

  const int srow = tid >> 3;
  const int scol = ((tid & 7) ^ (srow & 7)) * 8;
  const int brow_i = ((srow >> 5) << 6) + (srow & 31);
  const int bw = ((wid >> 2) << 6) + ((wid & 3) << 3);

  f32x4 acc[8][4];
#pragma unroll
  for (int i = 0; i < 8; ++i)
#pragma unroll
    for (int j = 0; j < 4; ++j) acc[i][j] = (f32x4){0.f, 0.f, 0.f, 0.f};

  STAGE_A(0, 0, 0, 0); STAGE_A(0, 0, 1, 0);
  STAGE_A(0, 1, 0, 0); STAGE_A(0, 1, 1, 0);
  STAGE_B(0, 0, 0, 0); STAGE_B(0, 0, 1, 0);
  STAGE_B(0, 1, 0, 0); STAGE_B(0, 1, 1, 0);
  STAGE_A(1, 0, 0, 1); STAGE_A(1, 0, 1, 1);
  STAGE_B(1, 0, 0, 1); STAGE_B(1, 0, 1, 1);

  const int NT = E_ / 64;  // 16 K-tiles
  for (int u = 0; u < NT; ++u) {
    const int cur = u & 1, nxt = cur ^ 1;
    __builtin_amdgcn_sched_barrier(0);
    if (u == NT - 1)
      asm volatile("s_waitcnt vmcnt(0)" ::: "memory");
    else
      asm volatile("s_waitcnt vmcnt(4)" ::: "memory");
    __builtin_amdgcn_sched_barrier(0);
    __builtin_amdgcn_s_barrier();

    short8 af[4][2], b0[2][2], b1[2][2];
#pragma unroll
    for (int i = 0; i < 4; ++i)
#pragma unroll
      for (int kk = 0; kk < 2; ++kk) {
        const int blk = (((kk * 4 + fg) ^ fr7) << 3);
        af[i][kk] = *(const short8*)
            &sA[cur][(wr * 128 + i * 16 + fr) * 64 + blk];
      }
#pragma unroll
    for (int j = 0; j < 2; ++j)
#pragma unroll
      for (int kk = 0; kk < 2; ++kk) {
        const int blk = (((kk * 4 + fg) ^ fr7) << 3);
        b0[j][kk] = *(const short8*)
            &sB[cur][(wc * 64 + j * 16 + fr) * 64 + blk];
        b1[j][kk] = *(const short8*)
            &sB[cur][(wc * 64 + (2 + j) * 16 + fr) * 64 + blk];
      }
    if (u + 1 < NT) {
      STAGE_A(nxt, 1, 0, u + 1); STAGE_A(nxt, 1, 1, u + 1);
      STAGE_B(nxt, 1, 0, u + 1); STAGE_B(nxt, 1, 1, u + 1);
    }
    asm volatile("s_waitcnt lgkmcnt(0)" ::: "memory");
    __builtin_amdgcn_sched_barrier(0);
    __builtin_amdgcn_s_setprio(1);
#pragma unroll
    for (int i = 0; i < 4; ++i)
#pragma unroll
      for (int kk = 0; kk < 2; ++kk) {
        acc[i][0] = __builtin_amdgcn_mfma_f32_16x16x32_bf16(af[i][kk], b0[0][kk], acc[i][0], 0, 0, 0);
        acc[i][1] = __builtin_amdgcn_mfma_f32_16x16x32_bf16(af[i][kk], b0[1][kk], acc[i][1], 0, 0, 0);
        acc[i][2] = __builtin_amdgcn_mfma_f32_16x16x32_bf16(af[i][kk], b1[0][kk], acc[i][2], 0, 0, 0);
        acc[i][3] = __builtin_amdgcn_mfma_f32_16x16x32_bf16(af[i][kk], b1[1][kk], acc[i][3], 0, 0, 0);
      }
    __builtin_amdgcn_s_setprio(0);
    __builtin_amdgcn_s_barrier();

#pragma unroll
    for (int i = 0; i < 4; ++i)
#pragma unroll
      for (int kk = 0; kk < 2; ++kk) {
        const int blk = (((kk * 4 + fg) ^ fr7) << 3);
        af[i][kk] = *(const short8*)
            &sA[cur][(wr * 128 + 64 + i * 16 + fr) * 64 + blk];
      }
    if (u + 2 < NT) {
      STAGE_A(cur, 0, 0, u + 2); STAGE_A(cur, 0, 1, u + 2);
      STAGE_B(cur, 0, 0, u + 2); STAGE_B(cur, 0, 1, u + 2);
    }
    asm volatile("s_waitcnt lgkmcnt(0)" ::: "memory");
    __builtin_amdgcn_sched_barrier(0);
    __builtin_amdgcn_s_setprio(1);
#pragma unroll
    for (int i = 0; i < 4; ++i)
#pragma unroll
      for (int kk = 0; kk < 2; ++kk) {
        acc[4 + i][0] = __builtin_amdgcn_mfma_f32_16x16x32_bf16(af[i][kk], b0[0][kk], acc[4 + i][0], 0, 0, 0);
        acc[4 + i][1] = __builtin_amdgcn_mfma_f32_16x16x32_bf16(af[i][kk], b0[1][kk], acc[4 + i][1], 0, 0, 0);
        acc[4 + i][2] = __builtin_amdgcn_mfma_f32_16x16x32_bf16(af[i][kk], b1[0][kk], acc[4 + i][2], 0, 0, 0);
        acc[4 + i][3] = __builtin_amdgcn_mfma_f32_16x16x32_bf16(af[i][kk], b1[1][kk], acc[4 + i][3], 0, 0, 0);
      }
    __builtin_amdgcn_s_setprio(0);
  }

  const int wsel = n0 >> 10;
  const float* bias = (wsel == 0) ? bq : (wsel == 1) ? bk : bv;
  float br[4];
#pragma unroll
  for (int j = 0; j < 4; ++j)
    br[j] = bias[(n0 & 1023) + wc * 64 + j * 16 + fr];

  if (wsel < 2) {
    unsigned short* T = (wsel == 0) ? QTb : KTb;
    const int b = m0 >> 12;
    const int lbase = (m0 & 4095) + wr * 128 + (fg << 2);
#pragma unroll
    for (int i = 0; i < 8; ++i)
#pragma unroll
      for (int j = 0; j < 4; ++j) {
        const int n_in = (n0 & 1023) + wc * 64 + j * 16 + fr;
        ushort4 v = make_ushort4(f2bf(acc[i][j][0] + br[j]),
                                 f2bf(acc[i][j][1] + br[j]),
                                 f2bf(acc[i][j][2] + br[j]),
                                 f2bf(acc[i][j][3] + br[j]));
        *(ushort4*)&T[((size_t)(b << 10) + n_in) * L_ + lbase + i * 16] = v;
      }
  } else {
#pragma unroll
    for (int i = 0; i < 8; ++i)
#pragma unroll
      for (int j = 0; j < 4; ++j) {
        const int n_in = (n0 & 1023) + wc * 64 + j * 16 + fr;
#pragma unroll
        for (int r = 0; r < 4; ++r) {
          const int m = m0 + wr * 128 + i * 16 + (fg << 2) + r;
          Vb[(size_t)m * E_ + n_in] = f2bf(acc[i][j][r] + br[j]);
        }
      }
  }
}

// ---------------------------------------------------------------------------
// Complex helpers.
// ---------------------------------------------------------------------------
__device__ __forceinline__ float2 cmulf(float2 a, float2 b) {
  return make_float2(a.x * b.x - a.y * b.y, a.x * b.y + a.y * b.x);
}

// Hermitian split + cross-spectrum for one packed FFT: z = q + i*k.
__device__ __forceinline__ float2 herm(float2 Zf, float2 Zc) {
  float ax = Zc.x, ay = -Zc.y;
  float qx = 0.5f * (Zf.x + ax), qy = 0.5f * (Zf.y + ay);
  float ux = Zf.x - ax, uy = Zf.y - ay;
  float kx = 0.5f * uy, ky = -0.5f * ux;
  return make_float2(qx * kx + qy * ky, qy * kx - qx * ky);
}

// ---------------------------------------------------------------------------
// Kernel 2a: per-(b,h,ds) partial cross-spectrum.
// 512 threads (8 waves), float2 Stockham, 2 butterflies/thread/stage,
// S in registers (4 bins/thread). LDS 64 KB -> 2 blocks/CU: two independent
// barrier domains per CU hide each other's latency.
// ---------------------------------------------------------------------------
__global__ __launch_bounds__(512) void corr_fft(
    const unsigned short* __restrict__ QTb,
    const unsigned short* __restrict__ KTb, float2* __restrict__ Spart) {
  __shared__ float2 bufA[L_];   // 32 KB
  __shared__ float2 bufB[L_];   // 32 KB

  const int bh = blockIdx.x, ds = blockIdx.y;
  const int b = bh >> 4, h = bh & (H_ - 1);
  const int tid = threadIdx.x;
  const float sign = -1.0f;

  // twiddles: stage st, butterfly j: w = exp(sign*2pi*i*(j&(Ns-1))/(4Ns)).
  // For Ns <= 512 both halves (j=tid, tid+512) share; stage 5 (Ns=1024) differs.
  float2 tw[6], tw5b;
  {
    const float TWO_PI = 6.28318530717958647692f;
#pragma unroll
    for (int st = 0; st < 6; ++st) {
      const int Ns = 1 << (2 * st);
      const int r = tid & (Ns - 1);
      float ang = sign * TWO_PI * (float)r / (float)(4 * Ns);
      __sincosf(ang, &tw[st].y, &tw[st].x);
    }
    const int r5 = (tid + 512) & 1023;
    float ang = sign * TWO_PI * (float)r5 / 4096.f;
    __sincosf(ang, &tw5b.y, &tw5b.x);
  }

  float2 s[4];
#pragma unroll
  for (int q = 0; q < 4; ++q) s[q] = make_float2(0.f, 0.f);

  const size_t baseQK = (size_t)(b * E_ + h * D_) * L_;

  for (int dd = 0; dd < 8; ++dd) {
    const int d = ds * 8 + dd;
    __syncthreads();  // previous pass's herm readers done
    const unsigned short* qp = QTb + baseQK + (size_t)d * L_;
    const unsigned short* kp = KTb + baseQK + (size_t)d * L_;
    {
      ushort4 qa = *(const ushort4*)(qp + tid * 8);
      ushort4 qb = *(const ushort4*)(qp + tid * 8 + 4);
      ushort4 ka = *(const ushort4*)(kp + tid * 8);
      ushort4 kb = *(const ushort4*)(kp + tid * 8 + 4);
      bufA[tid * 8 + 0] = make_float2(bf2f(qa.x), bf2f(ka.x));
      bufA[tid * 8 + 1] = make_float2(bf2f(qa.y), bf2f(ka.y));
      bufA[tid * 8 + 2] = make_float2(bf2f(qa.z), bf2f(ka.z));
      bufA[tid * 8 + 3] = make_float2(bf2f(qa.w), bf2f(ka.w));
      bufA[tid * 8 + 4] = make_float2(bf2f(qb.x), bf2f(kb.x));
      bufA[tid * 8 + 5] = make_float2(bf2f(qb.y), bf2f(kb.y));
      bufA[tid * 8 + 6] = make_float2(bf2f(qb.z), bf2f(kb.z));
      bufA[tid * 8 + 7] = make_float2(bf2f(qb.w), bf2f(kb.w));
    }
    // ---- 6-stage Stockham, 2 butterflies per thread per stage
    float2* cur = bufA;
    float2* nxt = bufB;
#pragma unroll
    for (int st = 0; st < 6; ++st) {
      const int Ns = 1 << (2 * st);
      __syncthreads();
#pragma unroll
      for (int h2 = 0; h2 < 2; ++h2) {
        const int j = tid + h2 * 512;
        float2 v0 = cur[j];
        float2 v1 = cur[j + 1024];
        float2 v2 = cur[j + 2048];
        float2 v3 = cur[j + 3072];
        const int r = j & (Ns - 1);
        if (st > 0) {
          float2 w1 = (st == 5 && h2 == 1) ? tw5b : tw[st];
          float2 w2 = cmulf(w1, w1);
          float2 w3 = cmulf(w2, w1);
          v1 = cmulf(v1, w1);
          v2 = cmulf(v2, w2);
          v3 = cmulf(v3, w3);
        }
        float2 t0 = make_float2(v0.x + v2.x, v0.y + v2.y);
        float2 t1 = make_float2(v0.x - v2.x, v0.y - v2.y);
        float2 t2 = make_float2(v1.x + v3.x, v1.y + v3.y);
        float2 t3 = make_float2(v1.x - v3.x, v1.y - v3.y);
        float2 t3i = make_float2(-sign * t3.y, sign * t3.x);
        const int idxD = ((j - r) << 2) + r;
        nxt[idxD]          = make_float2(t0.x + t2.x, t0.y + t2.y);
        nxt[idxD + Ns]     = make_float2(t1.x + t3i.x, t1.y + t3i.y);
        nxt[idxD + 2 * Ns] = make_float2(t0.x - t2.x, t0.y - t2.y);
        nxt[idxD + 3 * Ns] = make_float2(t1.x - t3i.x, t1.y - t3i.y);
      }
      float2* tmp = cur; cur = nxt; nxt = tmp;
    }
    __syncthreads();
    // result in bufA (6 swaps). Hermitian split + accumulate (4 bins/thread).
#pragma unroll
    for (int q = 0; q < 4; ++q) {
      const int f = tid + q * 512;
      float2 Zf = bufA[f];
      float2 Zc = bufA[(L_ - f) & (L_ - 1)];
      float2 r = herm(Zf, Zc);
      s[q].x += r.x;
      s[q].y += r.y;  // f==0: im is exactly 0, slot reused for Nyquist
    }
    if (tid == 0) {  // Nyquist f=2048, packed into s[0].y
      float2 Zf = bufA[2048];
      float2 r = herm(Zf, Zf);
      s[0].y += r.x;
    }
  }
  float2* out = Spart + (size_t)(bh * 8 + ds) * (L_ / 2);
#pragma unroll
  for (int q = 0; q < 4; ++q) out[tid + q * 512] = s[q];
}

// ---------------------------------------------------------------------------
// Radix-4 Stockham FFT (float2), N=4096, 1024 threads — used by corr_post.
// ---------------------------------------------------------------------------
__device__ __forceinline__ void fft_tw_init(float2* tw, int tid, float sign) {
  const float TWO_PI = 6.28318530717958647692f;
#pragma unroll
  for (int st = 0; st < 6; ++st) {
    const int Ns = 1 << (2 * st);
    const int r = tid & (Ns - 1);
    float ang = sign * TWO_PI * (float)r / (float)(4 * Ns);
    __sincosf(ang, &tw[st].y, &tw[st].x);
  }
}

__device__ __forceinline__ void fft4096_tw(float2* __restrict__ A,
                                           float2* __restrict__ Bb, int tid,
                                           float sign,
                                           const float2* __restrict__ tw) {
  float2* cur = A;
  float2* nxt = Bb;
#pragma unroll
  for (int st = 0; st < 6; ++st) {
    const int Ns = 1 << (2 * st);
    __syncthreads();
    const int j = tid;
    float2 v0 = cur[j];
    float2 v1 = cur[j + 1024];
    float2 v2 = cur[j + 2048];
    float2 v3 = cur[j + 3072];
    const int r = j & (Ns - 1);
    if (st > 0) {
      float2 w1 = tw[st];
      float2 w2 = cmulf(w1, w1);
      float2 w3 = cmulf(w2, w1);
      v1 = cmulf(v1, w1);
      v2 = cmulf(v2, w2);
      v3 = cmulf(v3, w3);
    }
    float2 t0 = make_float2(v0.x + v2.x, v0.y + v2.y);
    float2 t1 = make_float2(v0.x - v2.x, v0.y - v2.y);
    float2 t2 = make_float2(v1.x + v3.x, v1.y + v3.y);
    float2 t3 = make_float2(v1.x - v3.x, v1.y - v3.y);
    float2 t3i = make_float2(-sign * t3.y, sign * t3.x);
    const int idxD = ((j - r) << 2) + r;
    nxt[idxD]          = make_float2(t0.x + t2.x, t0.y + t2.y);
    nxt[idxD + Ns]     = make_float2(t1.x + t3i.x, t1.y + t3i.y);
    nxt[idxD + 2 * Ns] = make_float2(t0.x - t2.x, t0.y - t2.y);
    nxt[idxD + 3 * Ns] = make_float2(t1.x - t3i.x, t1.y - t3i.y);
    float2* tmp = cur; cur = nxt; nxt = tmp;
  }
  __syncthreads();
}

// ---------------------------------------------------------------------------
// Kernel 2b: per-(b,h) reduce partials -> inverse FFT -> softmax -> attnW.
// (attn@V moved to its own full-occupancy kernel.)
// ---------------------------------------------------------------------------
__global__ __launch_bounds__(1024) void corr_post(
    const float2* __restrict__ Spart, float* __restrict__ attnW) {
  __shared__ float2 bufA[L_];
  __shared__ float2 bufB[L_];
  __shared__ float red[1024];

  const int bh = blockIdx.x;
  const int tid = threadIdx.x;

  float2 tw[6];
  fft_tw_init(tw, tid, 1.0f);

  const float2* sp = Spart + (size_t)(bh * 8) * (L_ / 2);
  for (int f = tid; f < L_ / 2; f += 1024) {
    float2 s = make_float2(0.f, 0.f);
#pragma unroll
    for (int ds = 0; ds < 8; ++ds) {
      float2 p = sp[(size_t)ds * (L_ / 2) + f];
      s.x += p.x;
      s.y += p.y;
    }
    if (f == 0) {
      bufA[0] = make_float2(s.x, 0.f);
      bufA[L_ / 2] = make_float2(s.y, 0.f);
    } else {
      bufA[f] = s;
      bufA[L_ - f] = make_float2(s.x, -s.y);
    }
  }
  fft4096_tw(bufA, bufB, tid, 1.0f, tw);

  const float cscale = 1.0f / ((float)L_ * (float)D_);
  float lmax = -3.0e38f;
#pragma unroll
  for (int q = 0; q < 4; ++q) lmax = fmaxf(lmax, bufA[tid + q * 1024].x);
  red[tid] = lmax;
  __syncthreads();
  for (int s = 512; s > 0; s >>= 1) {
    if (tid < s) red[tid] = fmaxf(red[tid], red[tid + s]);
    __syncthreads();
  }
  const float gmax = red[0] * cscale;
  __syncthreads();
  float lsum = 0.f;
  float w4[4];
#pragma unroll
  for (int q = 0; q < 4; ++q) {
    w4[q] = __expf(bufA[tid + q * 1024].x * cscale - gmax);
    lsum += w4[q];
  }
  red[tid] = lsum;
  __syncthreads();
  for (int s = 512; s > 0; s >>= 1) {
    if (tid < s) red[tid] += red[tid + s];
    __syncthreads();
  }
  const float inv = 1.0f / red[0];
  float* aw = attnW + (size_t)bh * L_;
#pragma unroll
  for (int q = 0; q < 4; ++q) aw[tid + q * 1024] = w4[q] * inv;
}

// ---------------------------------------------------------------------------
// Kernel 2c: attn@V at full occupancy. Block (bh, dg): 8 d's x 4096 l.
// out_flat[b*E + d*H + h] = sum_l attnW[bh][l] * Vb[b,l,h*64+d].
// ---------------------------------------------------------------------------
__global__ __launch_bounds__(256) void attn_v(
    const float* __restrict__ attnW, const unsigned short* __restrict__ Vb,
    float* __restrict__ out_flat) {
  __shared__ float red[256];
  const int bh = blockIdx.x, dg = blockIdx.y;
  const int b = bh >> 4, h = bh & (H_ - 1);
  const int td = threadIdx.x & 7, tg = threadIdx.x >> 3;  // 8 d x 32 lgroups

  const float* aw = attnW + (size_t)bh * L_;
  const unsigned short* vb =
      Vb + (size_t)b * L_ * E_ + h * D_ + dg * 8 + td;
  float acc = 0.f;
  for (int l = tg; l < L_; l += 32)
    acc = fmaf(aw[l], bf2f(vb[(size_t)l * E_]), acc);
  red[tg * 8 + td] = acc;
  __syncthreads();
  for (int s = 16; s > 0; s >>= 1) {
    if (tg < s) red[tg * 8 + td] += red[(tg + s) * 8 + td];
    __syncthreads();
  }
  if (tg == 0)
    out_flat[b * E_ + (dg * 8 + td) * H_ + h] = red[td];
}

// ---------------------------------------------------------------------------
// Kernel 3: y[b,o] = bo[o] + sum_j flat[b,j] * Wo[o,j]  (128 blocks)
// ---------------------------------------------------------------------------
__global__ __launch_bounds__(256) void final_proj(
    const float* __restrict__ flat, const float* __restrict__ Wo,
    const float* __restrict__ bo, float* __restrict__ y) {
  __shared__ float sf[E_];
  const int b = blockIdx.y;
  const int o0 = blockIdx.x * 64;
  for (int j = threadIdx.x; j < E_; j += 256) sf[j] = flat[b * E_ + j];
  __syncthreads();
  const int oo = threadIdx.x >> 2, part = threadIdx.x & 3;
  const int o = o0 + oo;
  const float4* wr = (const float4*)(Wo + (size_t)o * E_) + part * 64;
  const float4* fr = (const float4*)sf + part * 64;
  float s = 0.f;
#pragma unroll 8
  for (int i = 0; i < 64; ++i) {
    float4 w = wr[i];
    float4 f = fr[i];
    s += w.x * f.x + w.y * f.y + w.z * f.z + w.w * f.w;
  }
  s += __shfl_xor(s, 1);
  s += __shfl_xor(s, 2);
  if (part == 0) y[b * E_ + o] = s + bo[o];
}

// ---------------------------------------------------------------------------
// Kernel 4: broadcast y (B,E) to out (B,L,E).
// ---------------------------------------------------------------------------
__global__ void broadcast_out(const float* __restrict__ y,
                              float4* __restrict__ out4) {
  const size_t total = (size_t)B_ * L_ * (E_ / 4);
  const float4* y4 = (const float4*)y;
  for (size_t i = (size_t)blockIdx.x * blockDim.x + threadIdx.x; i < total;
       i += (size_t)gridDim.x * blockDim.x) {
    size_t e4 = i & (E_ / 4 - 1);
    size_t b = i >> 20;
    out4[i] = y4[b * (E_ / 4) + e4];
  }
}

// ---------------------------------------------------------------------------
extern "C" void kernel_launch(void* const* d_in, const int* in_sizes, int n_in,
                              void* d_out, int out_size, void* d_ws,
                              size_t ws_size, hipStream_t stream) {
  const float* x  = (const float*)d_in[0];
  const float* Wq = (const float*)d_in[1];
  const float* bq = (const float*)d_in[2];
  const float* Wk = (const float*)d_in[3];
  const float* bk = (const float*)d_in[4];
  const float* Wv = (const float*)d_in[5];
  const float* bv = (const float*)d_in[6];
  const float* Wo = (const float*)d_in[7];
  const float* bo = (const float*)d_in[8];

  // ws layout (bytes):
  //   KTb bf16  @ 0          (67108864)
  //   Vb  bf16  @ 67108864   (67108864)
  //   Wb  bf16  @ 134217728  (6291456)
  //   Spart     @ 140509184  (16777216)
  //   flat      @ 157286400  (32768)
  //   y         @ 157319168  (32768)
  //   attnW     @ 157351936  (2097152)    => ~159.5 MB
  char* w = (char*)d_ws;
  unsigned short* KTb  = (unsigned short*)w;
  unsigned short* Vb   = (unsigned short*)(w + 67108864);
  unsigned short* Wb   = (unsigned short*)(w + 134217728);
  float2* Spart        = (float2*)(w + 140509184);
  float* flat          = (float*)(w + 157286400);
  float* y             = (float*)(w + 157319168);
  float* attnW         = (float*)(w + 157351936);
  unsigned short* QTb  = (unsigned short*)d_out;
  unsigned short* xb   = (unsigned short*)((char*)d_out + 67108864);

  conv_w<<<dim3(1024, 3), 256, 0, stream>>>(Wq, Wk, Wv, Wb);
  conv_x<<<dim3(2048), 256, 0, stream>>>(x, xb);
  qkv_gemm8<<<dim3(12, 128), 512, 0, stream>>>(xb, Wb, bq, bk, bv, QTb, KTb,
                                               Vb);
  corr_fft<<<dim3(B_ * H_, 8), 512, 0, stream>>>(QTb, KTb, Spart);
  corr_post<<<dim3(B_ * H_), 1024, 0, stream>>>(Spart, attnW);
  attn_v<<<dim3(B_ * H_, 8), 256, 0, stream>>>(attnW, Vb, flat);
  final_proj<<<dim3(16, B_), 256, 0, stream>>>(flat, Wo, bo, y);
  broadcast_out<<<dim3(2048), 256, 0, stream>>>(y, (float4*)d_out);
}

// Round 14
// 433.344 us; speedup vs baseline: 1.3181x; 1.0775x over previous
//
#include <hip/hip_runtime.h>
#include <hip/hip_bf16.h>
#include <math.h>

// Problem constants (AutoCorrelationAttention): B=8, L=4096, E=1024, H=16, D=64
#define B_ 8
#define L_ 4096
#define E_ 1024
#define H_ 16
#define D_ 64

typedef short short8 __attribute__((ext_vector_type(8)));
typedef float f32x4 __attribute__((ext_vector_type(4)));

__device__ __forceinline__ unsigned short f2bf(float f) {
  unsigned int u = __float_as_uint(f);
  unsigned int r = u + 0x7FFFu + ((u >> 16) & 1u);
  return (unsigned short)(r >> 16);
}
__device__ __forceinline__ float bf2f(unsigned short h) {
  return __uint_as_float(((unsigned int)h) << 16);
}

#define GLDS16(g, l)                                                     \
  __builtin_amdgcn_global_load_lds(                                      \
      (const __attribute__((address_space(1))) void*)(g),                \
      (__attribute__((address_space(3))) void*)(l), 16, 0, 0)

// ---------------------------------------------------------------------------
// Kernel 0a: convert Wq/Wk/Wv to bf16 (rounded), fused [3072][1024] layout.
// ---------------------------------------------------------------------------
__global__ __launch_bounds__(256) void conv_w(
    const float* __restrict__ Wq, const float* __restrict__ Wk,
    const float* __restrict__ Wv, unsigned short* __restrict__ Wb) {
  const int wsel = blockIdx.y;
  const float* W = (wsel == 0) ? Wq : (wsel == 1) ? Wk : Wv;
  size_t i = ((size_t)blockIdx.x * 256 + threadIdx.x) * 4;
  float4 f = *(const float4*)(W + i);
  size_t o = (size_t)wsel * (1024 * 1024) + i;
  *(ushort4*)(Wb + o) =
      make_ushort4(f2bf(f.x), f2bf(f.y), f2bf(f.z), f2bf(f.w));
}

// ---------------------------------------------------------------------------
// Kernel 0b: convert x (fp32) -> xb (bf16, rounded), natural layout.
// ---------------------------------------------------------------------------
__global__ __launch_bounds__(256) void conv_x(const float* __restrict__ x,
                                              unsigned short* __restrict__ xb) {
  const size_t total = (size_t)B_ * L_ * E_ / 8;
  for (size_t i = (size_t)blockIdx.x * blockDim.x + threadIdx.x; i < total;
       i += (size_t)gridDim.x * blockDim.x) {
    float4 a = ((const float4*)x)[i * 2];
    float4 b = ((const float4*)x)[i * 2 + 1];
    short8 v;
    v[0] = (short)f2bf(a.x); v[1] = (short)f2bf(a.y);
    v[2] = (short)f2bf(a.z); v[3] = (short)f2bf(a.w);
    v[4] = (short)f2bf(b.x); v[5] = (short)f2bf(b.y);
    v[6] = (short)f2bf(b.z); v[7] = (short)f2bf(b.w);
    *(short8*)&xb[i * 8] = v;
  }
}

// ---------------------------------------------------------------------------
// Kernel 1: fused QKV projection — 256x256 bf16 MFMA GEMM, 2-phase/K-tile
// with register-cached fragments. (unchanged from R10 — 212 us, MfmaUtil 43%)
// ---------------------------------------------------------------------------
#define STAGE_A(buf, h, s, t)                                                \
  GLDS16(xb + (size_t)(m0 + (s)*128 + (h)*64 + srow) * E_ + (t)*64 + scol,   \
         &sA[buf][((s)*128 + (h)*64 + wid * 8) * 64])
#define STAGE_B(buf, h, s, t)                                                \
  GLDS16(Wb + (size_t)(n0 + (s)*128 + (h)*32 + brow_i) * E_ + (t)*64 + scol, \
         &sB[buf][((s)*128 + (h)*32 + bw) * 64])

__global__ __launch_bounds__(512) void qkv_gemm8(
    const unsigned short* __restrict__ xb,
    const unsigned short* __restrict__ Wb, const float* __restrict__ bq,
    const float* __restrict__ bk, const float* __restrict__ bv,
    unsigned short* __restrict__ QTb, unsigned short* __restrict__ KTb,
    unsigned short* __restrict__ Vb) {
  __shared__ unsigned short sA[2][256 * 64];  // 2 x 32 KB
  __shared__ unsigned short sB[2][256 * 64];  // 2 x 32 KB

  const int tid = threadIdx.x;
  const int wid = tid >> 6, lane = tid & 63;
  const int wr = wid >> 2, wc = wid & 3;
  const int fr = lane & 15, fg = lane >> 4, fr7 = fr & 7;
  const int n0 = blockIdx.x * 256;
  const int m0 = blockIdx.y * 256;

  const int srow = tid >> 3;
  const int scol = ((tid & 7) ^ (srow & 7)) * 8;
  const int brow_i = ((srow >> 5) << 6) + (srow & 31);
  const int bw = ((wid >> 2) << 6) + ((wid & 3) << 3);

  f32x4 acc[8][4];
#pragma unroll
  for (int i = 0; i < 8; ++i)
#pragma unroll
    for (int j = 0; j < 4; ++j) acc[i][j] = (f32x4){0.f, 0.f, 0.f, 0.f};

  STAGE_A(0, 0, 0, 0); STAGE_A(0, 0, 1, 0);
  STAGE_A(0, 1, 0, 0); STAGE_A(0, 1, 1, 0);
  STAGE_B(0, 0, 0, 0); STAGE_B(0, 0, 1, 0);
  STAGE_B(0, 1, 0, 0); STAGE_B(0, 1, 1, 0);
  STAGE_A(1, 0, 0, 1); STAGE_A(1, 0, 1, 1);
  STAGE_B(1, 0, 0, 1); STAGE_B(1, 0, 1, 1);

  const int NT = E_ / 64;  // 16 K-tiles
  for (int u = 0; u < NT; ++u) {
    const int cur = u & 1, nxt = cur ^ 1;
    __builtin_amdgcn_sched_barrier(0);
    if (u == NT - 1)
      asm volatile("s_waitcnt vmcnt(0)" ::: "memory");
    else
      asm volatile("s_waitcnt vmcnt(4)" ::: "memory");
    __builtin_amdgcn_sched_barrier(0);
    __builtin_amdgcn_s_barrier();

    short8 af[4][2], b0[2][2], b1[2][2];
#pragma unroll
    for (int i = 0; i < 4; ++i)
#pragma unroll
      for (int kk = 0; kk < 2; ++kk) {
        const int blk = (((kk * 4 + fg) ^ fr7) << 3);
        af[i][kk] = *(const short8*)
            &sA[cur][(wr * 128 + i * 16 + fr) * 64 + blk];
      }
#pragma unroll
    for (int j = 0; j < 2; ++j)
#pragma unroll
      for (int kk = 0; kk < 2; ++kk) {
        const int blk = (((kk * 4 + fg) ^ fr7) << 3);
        b0[j][kk] = *(const short8*)
            &sB[cur][(wc * 64 + j * 16 + fr) * 64 + blk];
        b1[j][kk] = *(const short8*)
            &sB[cur][(wc * 64 + (2 + j) * 16 + fr) * 64 + blk];
      }
    if (u + 1 < NT) {
      STAGE_A(nxt, 1, 0, u + 1); STAGE_A(nxt, 1, 1, u + 1);
      STAGE_B(nxt, 1, 0, u + 1); STAGE_B(nxt, 1, 1, u + 1);
    }
    asm volatile("s_waitcnt lgkmcnt(0)" ::: "memory");
    __builtin_amdgcn_sched_barrier(0);
    __builtin_amdgcn_s_setprio(1);
#pragma unroll
    for (int i = 0; i < 4; ++i)
#pragma unroll
      for (int kk = 0; kk < 2; ++kk) {
        acc[i][0] = __builtin_amdgcn_mfma_f32_16x16x32_bf16(af[i][kk], b0[0][kk], acc[i][0], 0, 0, 0);
        acc[i][1] = __builtin_amdgcn_mfma_f32_16x16x32_bf16(af[i][kk], b0[1][kk], acc[i][1], 0, 0, 0);
        acc[i][2] = __builtin_amdgcn_mfma_f32_16x16x32_bf16(af[i][kk], b1[0][kk], acc[i][2], 0, 0, 0);
        acc[i][3] = __builtin_amdgcn_mfma_f32_16x16x32_bf16(af[i][kk], b1[1][kk], acc[i][3], 0, 0, 0);
      }
    __builtin_amdgcn_s_setprio(0);
    __builtin_amdgcn_s_barrier();

#pragma unroll
    for (int i = 0; i < 4; ++i)
#pragma unroll
      for (int kk = 0; kk < 2; ++kk) {
        const int blk = (((kk * 4 + fg) ^ fr7) << 3);
        af[i][kk] = *(const short8*)
            &sA[cur][(wr * 128 + 64 + i * 16 + fr) * 64 + blk];
      }
    if (u + 2 < NT) {
      STAGE_A(cur, 0, 0, u + 2); STAGE_A(cur, 0, 1, u + 2);
      STAGE_B(cur, 0, 0, u + 2); STAGE_B(cur, 0, 1, u + 2);
    }
    asm volatile("s_waitcnt lgkmcnt(0)" ::: "memory");
    __builtin_amdgcn_sched_barrier(0);
    __builtin_amdgcn_s_setprio(1);
#pragma unroll
    for (int i = 0; i < 4; ++i)
#pragma unroll
      for (int kk = 0; kk < 2; ++kk) {
        acc[4 + i][0] = __builtin_amdgcn_mfma_f32_16x16x32_bf16(af[i][kk], b0[0][kk], acc[4 + i][0], 0, 0, 0);
        acc[4 + i][1] = __builtin_amdgcn_mfma_f32_16x16x32_bf16(af[i][kk], b0[1][kk], acc[4 + i][1], 0, 0, 0);
        acc[4 + i][2] = __builtin_amdgcn_mfma_f32_16x16x32_bf16(af[i][kk], b1[0][kk], acc[4 + i][2], 0, 0, 0);
        acc[4 + i][3] = __builtin_amdgcn_mfma_f32_16x16x32_bf16(af[i][kk], b1[1][kk], acc[4 + i][3], 0, 0, 0);
      }
    __builtin_amdgcn_s_setprio(0);
  }

  const int wsel = n0 >> 10;
  const float* bias = (wsel == 0) ? bq : (wsel == 1) ? bk : bv;
  float br[4];
#pragma unroll
  for (int j = 0; j < 4; ++j)
    br[j] = bias[(n0 & 1023) + wc * 64 + j * 16 + fr];

  if (wsel < 2) {
    unsigned short* T = (wsel == 0) ? QTb : KTb;
    const int b = m0 >> 12;
    const int lbase = (m0 & 4095) + wr * 128 + (fg << 2);
#pragma unroll
    for (int i = 0; i < 8; ++i)
#pragma unroll
      for (int j = 0; j < 4; ++j) {
        const int n_in = (n0 & 1023) + wc * 64 + j * 16 + fr;
        ushort4 v = make_ushort4(f2bf(acc[i][j][0] + br[j]),
                                 f2bf(acc[i][j][1] + br[j]),
                                 f2bf(acc[i][j][2] + br[j]),
                                 f2bf(acc[i][j][3] + br[j]));
        *(ushort4*)&T[((size_t)(b << 10) + n_in) * L_ + lbase + i * 16] = v;
      }
  } else {
#pragma unroll
    for (int i = 0; i < 8; ++i)
#pragma unroll
      for (int j = 0; j < 4; ++j) {
        const int n_in = (n0 & 1023) + wc * 64 + j * 16 + fr;
#pragma unroll
        for (int r = 0; r < 4; ++r) {
          const int m = m0 + wr * 128 + i * 16 + (fg << 2) + r;
          Vb[(size_t)m * E_ + n_in] = f2bf(acc[i][j][r] + br[j]);
        }
      }
  }
}

// ---------------------------------------------------------------------------
// Complex helpers.
// ---------------------------------------------------------------------------
__device__ __forceinline__ float2 cmulf(float2 a, float2 b) {
  return make_float2(a.x * b.x - a.y * b.y, a.x * b.y + a.y * b.x);
}
// v * (c + i*sign*s)
__device__ __forceinline__ float2 twc(float2 v, float c, float s, float sign) {
  return make_float2(v.x * c - v.y * s * sign, v.x * s * sign + v.y * c);
}
// in-place DFT4, natural order out: X[k] = sum_m v[m] exp(sign*2pi*i*m*k/4)
__device__ __forceinline__ void dft4(float2& a, float2& b, float2& c,
                                     float2& d, float sign) {
  float2 t0 = make_float2(a.x + c.x, a.y + c.y);
  float2 t1 = make_float2(a.x - c.x, a.y - c.y);
  float2 t2 = make_float2(b.x + d.x, b.y + d.y);
  float2 t3 = make_float2(b.x - d.x, b.y - d.y);
  float2 t3i = make_float2(-sign * t3.y, sign * t3.x);
  a = make_float2(t0.x + t2.x, t0.y + t2.y);
  b = make_float2(t1.x + t3i.x, t1.y + t3i.y);
  c = make_float2(t0.x - t2.x, t0.y - t2.y);
  d = make_float2(t1.x - t3i.x, t1.y - t3i.y);
}
#define C45 0.707106781186548f

// Hermitian split + cross-spectrum for one packed FFT: z = q + i*k.
__device__ __forceinline__ float2 herm(float2 Zf, float2 Zc) {
  float ax = Zc.x, ay = -Zc.y;
  float qx = 0.5f * (Zf.x + ax), qy = 0.5f * (Zf.y + ay);
  float ux = Zf.x - ax, uy = Zf.y - ay;
  float kx = 0.5f * uy, ky = -0.5f * ux;
  return make_float2(qx * kx + qy * ky, qy * kx - qx * ky);
}

// XOR swizzle for float2 LDS arrays (involution; spreads Stockham scatter
// across banks). MUST be applied per element: swz(i+j) != swz(i)+j.
__device__ __forceinline__ int swz(int i) { return i ^ ((i >> 4) & 15); }

// ---------------------------------------------------------------------------
// Kernel 2a: per-(b,h,ds) partial cross-spectrum.
// Radix-8 Stockham (4096 = 8^4 -> 4 stages), 512 threads (8 waves),
// 1 butterfly/thread/stage, XOR-swizzled LDS (per-element), S in registers.
// LDS 64 KB -> 2 blocks/CU (two independent barrier domains).
// ---------------------------------------------------------------------------
__global__ __launch_bounds__(512) void corr_fft(
    const unsigned short* __restrict__ QTb,
    const unsigned short* __restrict__ KTb, float2* __restrict__ Spart) {
  __shared__ float2 bufA[L_];   // 32 KB
  __shared__ float2 bufB[L_];   // 32 KB

  const int bh = blockIdx.x, ds = blockIdx.y;
  const int b = bh >> 4, h = bh & (H_ - 1);
  const int tid = threadIdx.x;
  const float sign = -1.0f;

  // twiddle bases per stage st=1..3: exp(sign*2pi*i*(tid&(Ns-1))/(8*Ns)),
  // Ns = 8^st. Hoisted across the 8 FFTs.
  float2 twb[4];
  {
    const float TWO_PI = 6.28318530717958647692f;
#pragma unroll
    for (int st = 1; st < 4; ++st) {
      const int Ns = 1 << (3 * st);
      const int r = tid & (Ns - 1);
      float ang = sign * TWO_PI * (float)r / (float)(8 * Ns);
      __sincosf(ang, &twb[st].y, &twb[st].x);
    }
  }

  float2 s[4];
#pragma unroll
  for (int q = 0; q < 4; ++q) s[q] = make_float2(0.f, 0.f);

  const size_t baseQK = (size_t)(b * E_ + h * D_) * L_;

  for (int dd = 0; dd < 8; ++dd) {
    const int d = ds * 8 + dd;
    __syncthreads();  // previous pass's herm readers done
    const unsigned short* qp = QTb + baseQK + (size_t)d * L_;
    const unsigned short* kp = KTb + baseQK + (size_t)d * L_;
    {
      ushort4 qa = *(const ushort4*)(qp + tid * 8);
      ushort4 qb = *(const ushort4*)(qp + tid * 8 + 4);
      ushort4 ka = *(const ushort4*)(kp + tid * 8);
      ushort4 kb = *(const ushort4*)(kp + tid * 8 + 4);
      // swz per element: the 8-run shares one XOR constant c (same 16-block),
      // but (i^c)+j != (i+j)^c — so XOR each index. (R13's NaN bug.)
      const int i0 = tid * 8;
      const int c = (i0 >> 4) & 15;
      bufA[(i0 + 0) ^ c] = make_float2(bf2f(qa.x), bf2f(ka.x));
      bufA[(i0 + 1) ^ c] = make_float2(bf2f(qa.y), bf2f(ka.y));
      bufA[(i0 + 2) ^ c] = make_float2(bf2f(qa.z), bf2f(ka.z));
      bufA[(i0 + 3) ^ c] = make_float2(bf2f(qa.w), bf2f(ka.w));
      bufA[(i0 + 4) ^ c] = make_float2(bf2f(qb.x), bf2f(kb.x));
      bufA[(i0 + 5) ^ c] = make_float2(bf2f(qb.y), bf2f(kb.y));
      bufA[(i0 + 6) ^ c] = make_float2(bf2f(qb.z), bf2f(kb.z));
      bufA[(i0 + 7) ^ c] = make_float2(bf2f(qb.w), bf2f(kb.w));
    }
    // ---- 4-stage radix-8 Stockham
    float2* cur = bufA;
    float2* nxt = bufB;
#pragma unroll
    for (int st = 0; st < 4; ++st) {
      const int Ns = 1 << (3 * st);
      __syncthreads();
      const int j = tid;
      float2 v[8];
#pragma unroll
      for (int m = 0; m < 8; ++m) v[m] = cur[swz(j + (m << 9))];
      const int r = j & (Ns - 1);
      if (st > 0) {
        float2 w1 = twb[st];
        float2 w2 = cmulf(w1, w1);
        float2 w3 = cmulf(w2, w1);
        float2 w4 = cmulf(w2, w2);
        float2 w5 = cmulf(w4, w1);
        float2 w6 = cmulf(w4, w2);
        float2 w7 = cmulf(w4, w3);
        v[1] = cmulf(v[1], w1);
        v[2] = cmulf(v[2], w2);
        v[3] = cmulf(v[3], w3);
        v[4] = cmulf(v[4], w4);
        v[5] = cmulf(v[5], w5);
        v[6] = cmulf(v[6], w6);
        v[7] = cmulf(v[7], w7);
      }
      // DFT8 = 2x DFT4 (even/odd) + W8 combine
      float2 e0 = v[0], e1 = v[2], e2 = v[4], e3 = v[6];
      float2 o0 = v[1], o1 = v[3], o2 = v[5], o3 = v[7];
      dft4(e0, e1, e2, e3, sign);
      dft4(o0, o1, o2, o3, sign);
      o1 = twc(o1, C45, C45, sign);    // W8^1
      o2 = twc(o2, 0.0f, 1.0f, sign);  // W8^2 = i*sign
      o3 = twc(o3, -C45, C45, sign);   // W8^3
      const int idxD = ((j - r) << 3) + r;
      nxt[swz(idxD)]          = make_float2(e0.x + o0.x, e0.y + o0.y);
      nxt[swz(idxD + Ns)]     = make_float2(e1.x + o1.x, e1.y + o1.y);
      nxt[swz(idxD + 2 * Ns)] = make_float2(e2.x + o2.x, e2.y + o2.y);
      nxt[swz(idxD + 3 * Ns)] = make_float2(e3.x + o3.x, e3.y + o3.y);
      nxt[swz(idxD + 4 * Ns)] = make_float2(e0.x - o0.x, e0.y - o0.y);
      nxt[swz(idxD + 5 * Ns)] = make_float2(e1.x - o1.x, e1.y - o1.y);
      nxt[swz(idxD + 6 * Ns)] = make_float2(e2.x - o2.x, e2.y - o2.y);
      nxt[swz(idxD + 7 * Ns)] = make_float2(e3.x - o3.x, e3.y - o3.y);
      float2* tmp = cur; cur = nxt; nxt = tmp;
    }
    __syncthreads();
    // result in bufA (4 swaps). Hermitian split + accumulate (4 bins/thread).
#pragma unroll
    for (int q = 0; q < 4; ++q) {
      const int f = tid + q * 512;
      float2 Zf = bufA[swz(f)];
      float2 Zc = bufA[swz((L_ - f) & (L_ - 1))];
      float2 r = herm(Zf, Zc);
      s[q].x += r.x;
      s[q].y += r.y;  // f==0: im is exactly 0, slot reused for Nyquist
    }
    if (tid == 0) {  // Nyquist f=2048, packed into s[0].y
      float2 Zf = bufA[swz(2048)];
      float2 r = herm(Zf, Zf);
      s[0].y += r.x;
    }
  }
  float2* out = Spart + (size_t)(bh * 8 + ds) * (L_ / 2);
#pragma unroll
  for (int q = 0; q < 4; ++q) out[tid + q * 512] = s[q];
}

// ---------------------------------------------------------------------------
// Radix-4 Stockham FFT (float2), N=4096, 1024 threads — used by corr_post.
// ---------------------------------------------------------------------------
__device__ __forceinline__ void fft_tw_init(float2* tw, int tid, float sign) {
  const float TWO_PI = 6.28318530717958647692f;
#pragma unroll
  for (int st = 0; st < 6; ++st) {
    const int Ns = 1 << (2 * st);
    const int r = tid & (Ns - 1);
    float ang = sign * TWO_PI * (float)r / (float)(4 * Ns);
    __sincosf(ang, &tw[st].y, &tw[st].x);
  }
}

__device__ __forceinline__ void fft4096_tw(float2* __restrict__ A,
                                           float2* __restrict__ Bb, int tid,
                                           float sign,
                                           const float2* __restrict__ tw) {
  float2* cur = A;
  float2* nxt = Bb;
#pragma unroll
  for (int st = 0; st < 6; ++st) {
    const int Ns = 1 << (2 * st);
    __syncthreads();
    const int j = tid;
    float2 v0 = cur[j];
    float2 v1 = cur[j + 1024];
    float2 v2 = cur[j + 2048];
    float2 v3 = cur[j + 3072];
    const int r = j & (Ns - 1);
    if (st > 0) {
      float2 w1 = tw[st];
      float2 w2 = cmulf(w1, w1);
      float2 w3 = cmulf(w2, w1);
      v1 = cmulf(v1, w1);
      v2 = cmulf(v2, w2);
      v3 = cmulf(v3, w3);
    }
    float2 t0 = make_float2(v0.x + v2.x, v0.y + v2.y);
    float2 t1 = make_float2(v0.x - v2.x, v0.y - v2.y);
    float2 t2 = make_float2(v1.x + v3.x, v1.y + v3.y);
    float2 t3 = make_float2(v1.x - v3.x, v1.y - v3.y);
    float2 t3i = make_float2(-sign * t3.y, sign * t3.x);
    const int idxD = ((j - r) << 2) + r;
    nxt[idxD]          = make_float2(t0.x + t2.x, t0.y + t2.y);
    nxt[idxD + Ns]     = make_float2(t1.x + t3i.x, t1.y + t3i.y);
    nxt[idxD + 2 * Ns] = make_float2(t0.x - t2.x, t0.y - t2.y);
    nxt[idxD + 3 * Ns] = make_float2(t1.x - t3i.x, t1.y - t3i.y);
    float2* tmp = cur; cur = nxt; nxt = tmp;
  }
  __syncthreads();
}

// ---------------------------------------------------------------------------
// Kernel 2b: per-(b,h) reduce partials -> inverse FFT -> softmax -> attnW.
// ---------------------------------------------------------------------------
__global__ __launch_bounds__(1024) void corr_post(
    const float2* __restrict__ Spart, float* __restrict__ attnW) {
  __shared__ float2 bufA[L_];
  __shared__ float2 bufB[L_];
  __shared__ float red[1024];

  const int bh = blockIdx.x;
  const int tid = threadIdx.x;

  float2 tw[6];
  fft_tw_init(tw, tid, 1.0f);

  const float2* sp = Spart + (size_t)(bh * 8) * (L_ / 2);
  for (int f = tid; f < L_ / 2; f += 1024) {
    float2 s = make_float2(0.f, 0.f);
#pragma unroll
    for (int ds = 0; ds < 8; ++ds) {
      float2 p = sp[(size_t)ds * (L_ / 2) + f];
      s.x += p.x;
      s.y += p.y;
    }
    if (f == 0) {
      bufA[0] = make_float2(s.x, 0.f);
      bufA[L_ / 2] = make_float2(s.y, 0.f);
    } else {
      bufA[f] = s;
      bufA[L_ - f] = make_float2(s.x, -s.y);
    }
  }
  fft4096_tw(bufA, bufB, tid, 1.0f, tw);

  const float cscale = 1.0f / ((float)L_ * (float)D_);
  float lmax = -3.0e38f;
#pragma unroll
  for (int q = 0; q < 4; ++q) lmax = fmaxf(lmax, bufA[tid + q * 1024].x);
  red[tid] = lmax;
  __syncthreads();
  for (int s = 512; s > 0; s >>= 1) {
    if (tid < s) red[tid] = fmaxf(red[tid], red[tid + s]);
    __syncthreads();
  }
  const float gmax = red[0] * cscale;
  __syncthreads();
  float lsum = 0.f;
  float w4[4];
#pragma unroll
  for (int q = 0; q < 4; ++q) {
    w4[q] = __expf(bufA[tid + q * 1024].x * cscale - gmax);
    lsum += w4[q];
  }
  red[tid] = lsum;
  __syncthreads();
  for (int s = 512; s > 0; s >>= 1) {
    if (tid < s) red[tid] += red[tid + s];
    __syncthreads();
  }
  const float inv = 1.0f / red[0];
  float* aw = attnW + (size_t)bh * L_;
#pragma unroll
  for (int q = 0; q < 4; ++q) aw[tid + q * 1024] = w4[q] * inv;
}

// ---------------------------------------------------------------------------
// Kernel 2c: attn@V at full occupancy. Block (bh, dg): 8 d's x 4096 l.
// ---------------------------------------------------------------------------
__global__ __launch_bounds__(256) void attn_v(
    const float* __restrict__ attnW, const unsigned short* __restrict__ Vb,
    float* __restrict__ out_flat) {
  __shared__ float red[256];
  const int bh = blockIdx.x, dg = blockIdx.y;
  const int b = bh >> 4, h = bh & (H_ - 1);
  const int td = threadIdx.x & 7, tg = threadIdx.x >> 3;  // 8 d x 32 lgroups

  const float* aw = attnW + (size_t)bh * L_;
  const unsigned short* vb =
      Vb + (size_t)b * L_ * E_ + h * D_ + dg * 8 + td;
  float acc = 0.f;
  for (int l = tg; l < L_; l += 32)
    acc = fmaf(aw[l], bf2f(vb[(size_t)l * E_]), acc);
  red[tg * 8 + td] = acc;
  __syncthreads();
  for (int s = 16; s > 0; s >>= 1) {
    if (tg < s) red[tg * 8 + td] += red[(tg + s) * 8 + td];
    __syncthreads();
  }
  if (tg == 0)
    out_flat[b * E_ + (dg * 8 + td) * H_ + h] = red[td];
}

// ---------------------------------------------------------------------------
// Kernel 3: y[b,o] = bo[o] + sum_j flat[b,j] * Wo[o,j]  (128 blocks)
// ---------------------------------------------------------------------------
__global__ __launch_bounds__(256) void final_proj(
    const float* __restrict__ flat, const float* __restrict__ Wo,
    const float* __restrict__ bo, float* __restrict__ y) {
  __shared__ float sf[E_];
  const int b = blockIdx.y;
  const int o0 = blockIdx.x * 64;
  for (int j = threadIdx.x; j < E_; j += 256) sf[j] = flat[b * E_ + j];
  __syncthreads();
  const int oo = threadIdx.x >> 2, part = threadIdx.x & 3;
  const int o = o0 + oo;
  const float4* wr = (const float4*)(Wo + (size_t)o * E_) + part * 64;
  const float4* fr = (const float4*)sf + part * 64;
  float s = 0.f;
#pragma unroll 8
  for (int i = 0; i < 64; ++i) {
    float4 w = wr[i];
    float4 f = fr[i];
    s += w.x * f.x + w.y * f.y + w.z * f.z + w.w * f.w;
  }
  s += __shfl_xor(s, 1);
  s += __shfl_xor(s, 2);
  if (part == 0) y[b * E_ + o] = s + bo[o];
}

// ---------------------------------------------------------------------------
// Kernel 4: broadcast y (B,E) to out (B,L,E).
// ---------------------------------------------------------------------------
__global__ void broadcast_out(const float* __restrict__ y,
                              float4* __restrict__ out4) {
  const size_t total = (size_t)B_ * L_ * (E_ / 4);
  const float4* y4 = (const float4*)y;
  for (size_t i = (size_t)blockIdx.x * blockDim.x + threadIdx.x; i < total;
       i += (size_t)gridDim.x * blockDim.x) {
    size_t e4 = i & (E_ / 4 - 1);
    size_t b = i >> 20;
    out4[i] = y4[b * (E_ / 4) + e4];
  }
}

// ---------------------------------------------------------------------------
extern "C" void kernel_launch(void* const* d_in, const int* in_sizes, int n_in,
                              void* d_out, int out_size, void* d_ws,
                              size_t ws_size, hipStream_t stream) {
  const float* x  = (const float*)d_in[0];
  const float* Wq = (const float*)d_in[1];
  const float* bq = (const float*)d_in[2];
  const float* Wk = (const float*)d_in[3];
  const float* bk = (const float*)d_in[4];
  const float* Wv = (const float*)d_in[5];
  const float* bv = (const float*)d_in[6];
  const float* Wo = (const float*)d_in[7];
  const float* bo = (const float*)d_in[8];

  char* w = (char*)d_ws;
  unsigned short* KTb  = (unsigned short*)w;
  unsigned short* Vb   = (unsigned short*)(w + 67108864);
  unsigned short* Wb   = (unsigned short*)(w + 134217728);
  float2* Spart        = (float2*)(w + 140509184);
  float* flat          = (float*)(w + 157286400);
  float* y             = (float*)(w + 157319168);
  float* attnW         = (float*)(w + 157351936);
  unsigned short* QTb  = (unsigned short*)d_out;
  unsigned short* xb   = (unsigned short*)((char*)d_out + 67108864);

  conv_w<<<dim3(1024, 3), 256, 0, stream>>>(Wq, Wk, Wv, Wb);
  conv_x<<<dim3(2048), 256, 0, stream>>>(x, xb);
  qkv_gemm8<<<dim3(12, 128), 512, 0, stream>>>(xb, Wb, bq, bk, bv, QTb, KTb,
                                               Vb);
  corr_fft<<<dim3(B_ * H_, 8), 512, 0, stream>>>(QTb, KTb, Spart);
  corr_post<<<dim3(B_ * H_), 1024, 0, stream>>>(Spart, attnW);
  attn_v<<<dim3(B_ * H_, 8), 256, 0, stream>>>(attnW, Vb, flat);
  final_proj<<<dim3(16, B_), 256, 0, stream>>>(flat, Wo, bo, y);
  broadcast_out<<<dim3(2048), 256, 0, stream>>>(y, (float4*)d_out);
}

// Round 15
// 391.416 us; speedup vs baseline: 1.4593x; 1.1071x over previous
//
#include <hip/hip_runtime.h>
#include <hip/hip_bf16.h>
#include <math.h>

// Problem constants (AutoCorrelationAttention): B=8, L=4096, E=1024, H=16, D=64
#define B_ 8
#define L_ 4096
#define E_ 1024
#define H_ 16
#define D_ 64

typedef short short8 __attribute__((ext_vector_type(8)));
typedef float f32x4 __attribute__((ext_vector_type(4)));

__device__ __forceinline__ unsigned short f2bf(float f) {
  unsigned int u = __float_as_uint(f);
  unsigned int r = u + 0x7FFFu + ((u >> 16) & 1u);
  return (unsigned short)(r >> 16);
}
__device__ __forceinline__ float bf2f(unsigned short h) {
  return __uint_as_float(((unsigned int)h) << 16);
}

#define GLDS16(g, l)                                                     \
  __builtin_amdgcn_global_load_lds(                                      \
      (const __attribute__((address_space(1))) void*)(g),                \
      (__attribute__((address_space(3))) void*)(l), 16, 0, 0)

// ---------------------------------------------------------------------------
// Kernel 0a: convert Wq/Wk/Wv to bf16 (rounded), fused [3072][1024] layout.
// ---------------------------------------------------------------------------
__global__ __launch_bounds__(256) void conv_w(
    const float* __restrict__ Wq, const float* __restrict__ Wk,
    const float* __restrict__ Wv, unsigned short* __restrict__ Wb) {
  const int wsel = blockIdx.y;
  const float* W = (wsel == 0) ? Wq : (wsel == 1) ? Wk : Wv;
  size_t i = ((size_t)blockIdx.x * 256 + threadIdx.x) * 4;
  float4 f = *(const float4*)(W + i);
  size_t o = (size_t)wsel * (1024 * 1024) + i;
  *(ushort4*)(Wb + o) =
      make_ushort4(f2bf(f.x), f2bf(f.y), f2bf(f.z), f2bf(f.w));
}

// ---------------------------------------------------------------------------
// Kernel 0b: convert x (fp32) -> xb (bf16, rounded), natural layout.
// ---------------------------------------------------------------------------
__global__ __launch_bounds__(256) void conv_x(const float* __restrict__ x,
                                              unsigned short* __restrict__ xb) {
  const size_t total = (size_t)B_ * L_ * E_ / 8;
  for (size_t i = (size_t)blockIdx.x * blockDim.x + threadIdx.x; i < total;
       i += (size_t)gridDim.x * blockDim.x) {
    float4 a = ((const float4*)x)[i * 2];
    float4 b = ((const float4*)x)[i * 2 + 1];
    short8 v;
    v[0] = (short)f2bf(a.x); v[1] = (short)f2bf(a.y);
    v[2] = (short)f2bf(a.z); v[3] = (short)f2bf(a.w);
    v[4] = (short)f2bf(b.x); v[5] = (short)f2bf(b.y);
    v[6] = (short)f2bf(b.z); v[7] = (short)f2bf(b.w);
    *(short8*)&xb[i * 8] = v;
  }
}

// ---------------------------------------------------------------------------
// Kernel 1: fused QKV projection — 256x256 bf16 MFMA GEMM, 2-phase/K-tile
// with register-cached fragments. Epilogue unified: Q, K, AND V all stored
// transposed bf16 (B, E, L) via ushort4-along-L (V was scalar stores before).
// ---------------------------------------------------------------------------
#define STAGE_A(buf, h, s, t)                                                \
  GLDS16(xb + (size_t)(m0 + (s)*128 + (h)*64 + srow) * E_ + (t)*64 + scol,   \
         &sA[buf][((s)*128 + (h)*64 + wid * 8) * 64])
#define STAGE_B(buf, h, s, t)                                                \
  GLDS16(Wb + (size_t)(n0 + (s)*128 + (h)*32 + brow_i) * E_ + (t)*64 + scol, \
         &sB[buf][((s)*128 + (h)*32 + bw) * 64])

__global__ __launch_bounds__(512) void qkv_gemm8(
    const unsigned short* __restrict__ xb,
    const unsigned short* __restrict__ Wb, const float* __restrict__ bq,
    const float* __restrict__ bk, const float* __restrict__ bv,
    unsigned short* __restrict__ QTb, unsigned short* __restrict__ KTb,
    unsigned short* __restrict__ VTb) {
  __shared__ unsigned short sA[2][256 * 64];  // 2 x 32 KB
  __shared__ unsigned short sB[2][256 * 64];  // 2 x 32 KB

  const int tid = threadIdx.x;
  const int wid = tid >> 6, lane = tid & 63;
  const int wr = wid >> 2, wc = wid & 3;
  const int fr = lane & 15, fg = lane >> 4, fr7 = fr & 7;
  const int n0 = blockIdx.x * 256;
  const int m0 = blockIdx.y * 256;

  const int srow = tid >> 3;
  const int scol = ((tid & 7) ^ (srow & 7)) * 8;
  const int brow_i = ((srow >> 5) << 6) + (srow & 31);
  const int bw = ((wid >> 2) << 6) + ((wid & 3) << 3);

  f32x4 acc[8][4];
#pragma unroll
  for (int i = 0; i < 8; ++i)
#pragma unroll
    for (int j = 0; j < 4; ++j) acc[i][j] = (f32x4){0.f, 0.f, 0.f, 0.f};

  STAGE_A(0, 0, 0, 0); STAGE_A(0, 0, 1, 0);
  STAGE_A(0, 1, 0, 0); STAGE_A(0, 1, 1, 0);
  STAGE_B(0, 0, 0, 0); STAGE_B(0, 0, 1, 0);
  STAGE_B(0, 1, 0, 0); STAGE_B(0, 1, 1, 0);
  STAGE_A(1, 0, 0, 1); STAGE_A(1, 0, 1, 1);
  STAGE_B(1, 0, 0, 1); STAGE_B(1, 0, 1, 1);

  const int NT = E_ / 64;  // 16 K-tiles
  for (int u = 0; u < NT; ++u) {
    const int cur = u & 1, nxt = cur ^ 1;
    __builtin_amdgcn_sched_barrier(0);
    if (u == NT - 1)
      asm volatile("s_waitcnt vmcnt(0)" ::: "memory");
    else
      asm volatile("s_waitcnt vmcnt(4)" ::: "memory");
    __builtin_amdgcn_sched_barrier(0);
    __builtin_amdgcn_s_barrier();

    short8 af[4][2], b0[2][2], b1[2][2];
#pragma unroll
    for (int i = 0; i < 4; ++i)
#pragma unroll
      for (int kk = 0; kk < 2; ++kk) {
        const int blk = (((kk * 4 + fg) ^ fr7) << 3);
        af[i][kk] = *(const short8*)
            &sA[cur][(wr * 128 + i * 16 + fr) * 64 + blk];
      }
#pragma unroll
    for (int j = 0; j < 2; ++j)
#pragma unroll
      for (int kk = 0; kk < 2; ++kk) {
        const int blk = (((kk * 4 + fg) ^ fr7) << 3);
        b0[j][kk] = *(const short8*)
            &sB[cur][(wc * 64 + j * 16 + fr) * 64 + blk];
        b1[j][kk] = *(const short8*)
            &sB[cur][(wc * 64 + (2 + j) * 16 + fr) * 64 + blk];
      }
    if (u + 1 < NT) {
      STAGE_A(nxt, 1, 0, u + 1); STAGE_A(nxt, 1, 1, u + 1);
      STAGE_B(nxt, 1, 0, u + 1); STAGE_B(nxt, 1, 1, u + 1);
    }
    asm volatile("s_waitcnt lgkmcnt(0)" ::: "memory");
    __builtin_amdgcn_sched_barrier(0);
    __builtin_amdgcn_s_setprio(1);
#pragma unroll
    for (int i = 0; i < 4; ++i)
#pragma unroll
      for (int kk = 0; kk < 2; ++kk) {
        acc[i][0] = __builtin_amdgcn_mfma_f32_16x16x32_bf16(af[i][kk], b0[0][kk], acc[i][0], 0, 0, 0);
        acc[i][1] = __builtin_amdgcn_mfma_f32_16x16x32_bf16(af[i][kk], b0[1][kk], acc[i][1], 0, 0, 0);
        acc[i][2] = __builtin_amdgcn_mfma_f32_16x16x32_bf16(af[i][kk], b1[0][kk], acc[i][2], 0, 0, 0);
        acc[i][3] = __builtin_amdgcn_mfma_f32_16x16x32_bf16(af[i][kk], b1[1][kk], acc[i][3], 0, 0, 0);
      }
    __builtin_amdgcn_s_setprio(0);
    __builtin_amdgcn_s_barrier();

#pragma unroll
    for (int i = 0; i < 4; ++i)
#pragma unroll
      for (int kk = 0; kk < 2; ++kk) {
        const int blk = (((kk * 4 + fg) ^ fr7) << 3);
        af[i][kk] = *(const short8*)
            &sA[cur][(wr * 128 + 64 + i * 16 + fr) * 64 + blk];
      }
    if (u + 2 < NT) {
      STAGE_A(cur, 0, 0, u + 2); STAGE_A(cur, 0, 1, u + 2);
      STAGE_B(cur, 0, 0, u + 2); STAGE_B(cur, 0, 1, u + 2);
    }
    asm volatile("s_waitcnt lgkmcnt(0)" ::: "memory");
    __builtin_amdgcn_sched_barrier(0);
    __builtin_amdgcn_s_setprio(1);
#pragma unroll
    for (int i = 0; i < 4; ++i)
#pragma unroll
      for (int kk = 0; kk < 2; ++kk) {
        acc[4 + i][0] = __builtin_amdgcn_mfma_f32_16x16x32_bf16(af[i][kk], b0[0][kk], acc[4 + i][0], 0, 0, 0);
        acc[4 + i][1] = __builtin_amdgcn_mfma_f32_16x16x32_bf16(af[i][kk], b0[1][kk], acc[4 + i][1], 0, 0, 0);
        acc[4 + i][2] = __builtin_amdgcn_mfma_f32_16x16x32_bf16(af[i][kk], b1[0][kk], acc[4 + i][2], 0, 0, 0);
        acc[4 + i][3] = __builtin_amdgcn_mfma_f32_16x16x32_bf16(af[i][kk], b1[1][kk], acc[4 + i][3], 0, 0, 0);
      }
    __builtin_amdgcn_s_setprio(0);
  }

  // ---- unified transposed epilogue (Q, K, V all (B,E,L) bf16)
  const int wsel = n0 >> 10;
  const float* bias = (wsel == 0) ? bq : (wsel == 1) ? bk : bv;
  unsigned short* T = (wsel == 0) ? QTb : (wsel == 1) ? KTb : VTb;
  float br[4];
#pragma unroll
  for (int j = 0; j < 4; ++j)
    br[j] = bias[(n0 & 1023) + wc * 64 + j * 16 + fr];

  const int b = m0 >> 12;
  const int lbase = (m0 & 4095) + wr * 128 + (fg << 2);
#pragma unroll
  for (int i = 0; i < 8; ++i)
#pragma unroll
    for (int j = 0; j < 4; ++j) {
      const int n_in = (n0 & 1023) + wc * 64 + j * 16 + fr;
      ushort4 v = make_ushort4(f2bf(acc[i][j][0] + br[j]),
                               f2bf(acc[i][j][1] + br[j]),
                               f2bf(acc[i][j][2] + br[j]),
                               f2bf(acc[i][j][3] + br[j]));
      *(ushort4*)&T[((size_t)(b << 10) + n_in) * L_ + lbase + i * 16] = v;
    }
}

// ---------------------------------------------------------------------------
// Complex helpers.
// ---------------------------------------------------------------------------
__device__ __forceinline__ float2 cmulf(float2 a, float2 b) {
  return make_float2(a.x * b.x - a.y * b.y, a.x * b.y + a.y * b.x);
}
// v * (c + i*sign*s)
__device__ __forceinline__ float2 twc(float2 v, float c, float s, float sign) {
  return make_float2(v.x * c - v.y * s * sign, v.x * s * sign + v.y * c);
}
// in-place DFT4, natural order out
__device__ __forceinline__ void dft4(float2& a, float2& b, float2& c,
                                     float2& d, float sign) {
  float2 t0 = make_float2(a.x + c.x, a.y + c.y);
  float2 t1 = make_float2(a.x - c.x, a.y - c.y);
  float2 t2 = make_float2(b.x + d.x, b.y + d.y);
  float2 t3 = make_float2(b.x - d.x, b.y - d.y);
  float2 t3i = make_float2(-sign * t3.y, sign * t3.x);
  a = make_float2(t0.x + t2.x, t0.y + t2.y);
  b = make_float2(t1.x + t3i.x, t1.y + t3i.y);
  c = make_float2(t0.x - t2.x, t0.y - t2.y);
  d = make_float2(t1.x - t3i.x, t1.y - t3i.y);
}
#define C45 0.707106781186548f

// Hermitian split + cross-spectrum for one packed FFT: z = q + i*k.
__device__ __forceinline__ float2 herm(float2 Zf, float2 Zc) {
  float ax = Zc.x, ay = -Zc.y;
  float qx = 0.5f * (Zf.x + ax), qy = 0.5f * (Zf.y + ay);
  float ux = Zf.x - ax, uy = Zf.y - ay;
  float kx = 0.5f * uy, ky = -0.5f * ux;
  return make_float2(qx * kx + qy * ky, qy * kx - qx * ky);
}

// XOR swizzle for float2 LDS arrays (involution; spreads Stockham scatter
// across banks). MUST be applied per element: swz(i+j) != swz(i)+j.
__device__ __forceinline__ int swz(int i) { return i ^ ((i >> 4) & 15); }

// ---------------------------------------------------------------------------
// Kernel 2a: per-(b,h,ds) partial cross-spectrum.
// Radix-8 Stockham (4 stages), 512 threads, XOR-swizzled LDS, S in regs.
// ---------------------------------------------------------------------------
__global__ __launch_bounds__(512) void corr_fft(
    const unsigned short* __restrict__ QTb,
    const unsigned short* __restrict__ KTb, float2* __restrict__ Spart) {
  __shared__ float2 bufA[L_];   // 32 KB
  __shared__ float2 bufB[L_];   // 32 KB

  const int bh = blockIdx.x, ds = blockIdx.y;
  const int b = bh >> 4, h = bh & (H_ - 1);
  const int tid = threadIdx.x;
  const float sign = -1.0f;

  float2 twb[4];
  {
    const float TWO_PI = 6.28318530717958647692f;
#pragma unroll
    for (int st = 1; st < 4; ++st) {
      const int Ns = 1 << (3 * st);
      const int r = tid & (Ns - 1);
      float ang = sign * TWO_PI * (float)r / (float)(8 * Ns);
      __sincosf(ang, &twb[st].y, &twb[st].x);
    }
  }

  float2 s[4];
#pragma unroll
  for (int q = 0; q < 4; ++q) s[q] = make_float2(0.f, 0.f);

  const size_t baseQK = (size_t)(b * E_ + h * D_) * L_;

  for (int dd = 0; dd < 8; ++dd) {
    const int d = ds * 8 + dd;
    __syncthreads();
    const unsigned short* qp = QTb + baseQK + (size_t)d * L_;
    const unsigned short* kp = KTb + baseQK + (size_t)d * L_;
    {
      ushort4 qa = *(const ushort4*)(qp + tid * 8);
      ushort4 qb = *(const ushort4*)(qp + tid * 8 + 4);
      ushort4 ka = *(const ushort4*)(kp + tid * 8);
      ushort4 kb = *(const ushort4*)(kp + tid * 8 + 4);
      const int i0 = tid * 8;
      const int c = (i0 >> 4) & 15;
      bufA[(i0 + 0) ^ c] = make_float2(bf2f(qa.x), bf2f(ka.x));
      bufA[(i0 + 1) ^ c] = make_float2(bf2f(qa.y), bf2f(ka.y));
      bufA[(i0 + 2) ^ c] = make_float2(bf2f(qa.z), bf2f(ka.z));
      bufA[(i0 + 3) ^ c] = make_float2(bf2f(qa.w), bf2f(ka.w));
      bufA[(i0 + 4) ^ c] = make_float2(bf2f(qb.x), bf2f(kb.x));
      bufA[(i0 + 5) ^ c] = make_float2(bf2f(qb.y), bf2f(kb.y));
      bufA[(i0 + 6) ^ c] = make_float2(bf2f(qb.z), bf2f(kb.z));
      bufA[(i0 + 7) ^ c] = make_float2(bf2f(qb.w), bf2f(kb.w));
    }
    float2* cur = bufA;
    float2* nxt = bufB;
#pragma unroll
    for (int st = 0; st < 4; ++st) {
      const int Ns = 1 << (3 * st);
      __syncthreads();
      const int j = tid;
      float2 v[8];
#pragma unroll
      for (int m = 0; m < 8; ++m) v[m] = cur[swz(j + (m << 9))];
      const int r = j & (Ns - 1);
      if (st > 0) {
        float2 w1 = twb[st];
        float2 w2 = cmulf(w1, w1);
        float2 w3 = cmulf(w2, w1);
        float2 w4 = cmulf(w2, w2);
        float2 w5 = cmulf(w4, w1);
        float2 w6 = cmulf(w4, w2);
        float2 w7 = cmulf(w4, w3);
        v[1] = cmulf(v[1], w1);
        v[2] = cmulf(v[2], w2);
        v[3] = cmulf(v[3], w3);
        v[4] = cmulf(v[4], w4);
        v[5] = cmulf(v[5], w5);
        v[6] = cmulf(v[6], w6);
        v[7] = cmulf(v[7], w7);
      }
      float2 e0 = v[0], e1 = v[2], e2 = v[4], e3 = v[6];
      float2 o0 = v[1], o1 = v[3], o2 = v[5], o3 = v[7];
      dft4(e0, e1, e2, e3, sign);
      dft4(o0, o1, o2, o3, sign);
      o1 = twc(o1, C45, C45, sign);
      o2 = twc(o2, 0.0f, 1.0f, sign);
      o3 = twc(o3, -C45, C45, sign);
      const int idxD = ((j - r) << 3) + r;
      nxt[swz(idxD)]          = make_float2(e0.x + o0.x, e0.y + o0.y);
      nxt[swz(idxD + Ns)]     = make_float2(e1.x + o1.x, e1.y + o1.y);
      nxt[swz(idxD + 2 * Ns)] = make_float2(e2.x + o2.x, e2.y + o2.y);
      nxt[swz(idxD + 3 * Ns)] = make_float2(e3.x + o3.x, e3.y + o3.y);
      nxt[swz(idxD + 4 * Ns)] = make_float2(e0.x - o0.x, e0.y - o0.y);
      nxt[swz(idxD + 5 * Ns)] = make_float2(e1.x - o1.x, e1.y - o1.y);
      nxt[swz(idxD + 6 * Ns)] = make_float2(e2.x - o2.x, e2.y - o2.y);
      nxt[swz(idxD + 7 * Ns)] = make_float2(e3.x - o3.x, e3.y - o3.y);
      float2* tmp = cur; cur = nxt; nxt = tmp;
    }
    __syncthreads();
#pragma unroll
    for (int q = 0; q < 4; ++q) {
      const int f = tid + q * 512;
      float2 Zf = bufA[swz(f)];
      float2 Zc = bufA[swz((L_ - f) & (L_ - 1))];
      float2 r = herm(Zf, Zc);
      s[q].x += r.x;
      s[q].y += r.y;
    }
    if (tid == 0) {
      float2 Zf = bufA[swz(2048)];
      float2 r = herm(Zf, Zf);
      s[0].y += r.x;
    }
  }
  float2* out = Spart + (size_t)(bh * 8 + ds) * (L_ / 2);
#pragma unroll
  for (int q = 0; q < 4; ++q) out[tid + q * 512] = s[q];
}

// ---------------------------------------------------------------------------
// Radix-4 Stockham FFT (float2), N=4096, 1024 threads — used by corr_post.
// ---------------------------------------------------------------------------
__device__ __forceinline__ void fft_tw_init(float2* tw, int tid, float sign) {
  const float TWO_PI = 6.28318530717958647692f;
#pragma unroll
  for (int st = 0; st < 6; ++st) {
    const int Ns = 1 << (2 * st);
    const int r = tid & (Ns - 1);
    float ang = sign * TWO_PI * (float)r / (float)(4 * Ns);
    __sincosf(ang, &tw[st].y, &tw[st].x);
  }
}

__device__ __forceinline__ void fft4096_tw(float2* __restrict__ A,
                                           float2* __restrict__ Bb, int tid,
                                           float sign,
                                           const float2* __restrict__ tw) {
  float2* cur = A;
  float2* nxt = Bb;
#pragma unroll
  for (int st = 0; st < 6; ++st) {
    const int Ns = 1 << (2 * st);
    __syncthreads();
    const int j = tid;
    float2 v0 = cur[j];
    float2 v1 = cur[j + 1024];
    float2 v2 = cur[j + 2048];
    float2 v3 = cur[j + 3072];
    const int r = j & (Ns - 1);
    if (st > 0) {
      float2 w1 = tw[st];
      float2 w2 = cmulf(w1, w1);
      float2 w3 = cmulf(w2, w1);
      v1 = cmulf(v1, w1);
      v2 = cmulf(v2, w2);
      v3 = cmulf(v3, w3);
    }
    float2 t0 = make_float2(v0.x + v2.x, v0.y + v2.y);
    float2 t1 = make_float2(v0.x - v2.x, v0.y - v2.y);
    float2 t2 = make_float2(v1.x + v3.x, v1.y + v3.y);
    float2 t3 = make_float2(v1.x - v3.x, v1.y - v3.y);
    float2 t3i = make_float2(-sign * t3.y, sign * t3.x);
    const int idxD = ((j - r) << 2) + r;
    nxt[idxD]          = make_float2(t0.x + t2.x, t0.y + t2.y);
    nxt[idxD + Ns]     = make_float2(t1.x + t3i.x, t1.y + t3i.y);
    nxt[idxD + 2 * Ns] = make_float2(t0.x - t2.x, t0.y - t2.y);
    nxt[idxD + 3 * Ns] = make_float2(t1.x - t3i.x, t1.y - t3i.y);
    float2* tmp = cur; cur = nxt; nxt = tmp;
  }
  __syncthreads();
}

// ---------------------------------------------------------------------------
// Kernel 2b: per-(b,h) reduce partials -> inverse FFT -> softmax -> attnW.
// ---------------------------------------------------------------------------
__global__ __launch_bounds__(1024) void corr_post(
    const float2* __restrict__ Spart, float* __restrict__ attnW) {
  __shared__ float2 bufA[L_];
  __shared__ float2 bufB[L_];
  __shared__ float red[1024];

  const int bh = blockIdx.x;
  const int tid = threadIdx.x;

  float2 tw[6];
  fft_tw_init(tw, tid, 1.0f);

  const float2* sp = Spart + (size_t)(bh * 8) * (L_ / 2);
  for (int f = tid; f < L_ / 2; f += 1024) {
    float2 s = make_float2(0.f, 0.f);
#pragma unroll
    for (int ds = 0; ds < 8; ++ds) {
      float2 p = sp[(size_t)ds * (L_ / 2) + f];
      s.x += p.x;
      s.y += p.y;
    }
    if (f == 0) {
      bufA[0] = make_float2(s.x, 0.f);
      bufA[L_ / 2] = make_float2(s.y, 0.f);
    } else {
      bufA[f] = s;
      bufA[L_ - f] = make_float2(s.x, -s.y);
    }
  }
  fft4096_tw(bufA, bufB, tid, 1.0f, tw);

  const float cscale = 1.0f / ((float)L_ * (float)D_);
  float lmax = -3.0e38f;
#pragma unroll
  for (int q = 0; q < 4; ++q) lmax = fmaxf(lmax, bufA[tid + q * 1024].x);
  red[tid] = lmax;
  __syncthreads();
  for (int s = 512; s > 0; s >>= 1) {
    if (tid < s) red[tid] = fmaxf(red[tid], red[tid + s]);
    __syncthreads();
  }
  const float gmax = red[0] * cscale;
  __syncthreads();
  float lsum = 0.f;
  float w4[4];
#pragma unroll
  for (int q = 0; q < 4; ++q) {
    w4[q] = __expf(bufA[tid + q * 1024].x * cscale - gmax);
    lsum += w4[q];
  }
  red[tid] = lsum;
  __syncthreads();
  for (int s = 512; s > 0; s >>= 1) {
    if (tid < s) red[tid] += red[tid + s];
    __syncthreads();
  }
  const float inv = 1.0f / red[0];
  float* aw = attnW + (size_t)bh * L_;
#pragma unroll
  for (int q = 0; q < 4; ++q) aw[tid + q * 1024] = w4[q] * inv;
}

// ---------------------------------------------------------------------------
// Kernel 2c: attn@V with transposed V (B,E,L) — fully coalesced reads.
// Block (bh, dg): 8 d-rows x 4096 l. 256 thr = 8 rows x 32 chunk-lanes.
// ---------------------------------------------------------------------------
__global__ __launch_bounds__(256) void attn_v(
    const float* __restrict__ attnW, const unsigned short* __restrict__ VTb,
    float* __restrict__ out_flat) {
  __shared__ float saw[L_];  // 16 KB
  const int bh = blockIdx.x, dg = blockIdx.y;
  const int b = bh >> 4, h = bh & (H_ - 1);
  const float* aw = attnW + (size_t)bh * L_;
  for (int i = threadIdx.x; i < L_ / 4; i += 256)
    *(float4*)&saw[i * 4] = *(const float4*)&aw[i * 4];
  __syncthreads();

  const int r = threadIdx.x >> 5, c = threadIdx.x & 31;
  const int d = dg * 8 + r;
  const unsigned short* vrow =
      VTb + ((size_t)(b * E_ + h * D_ + d)) * L_;
  float acc = 0.f;
#pragma unroll 4
  for (int i = 0; i < 32; ++i) {
    const int l0 = i * 128 + c * 4;  // strided 4-elem chunks (bank-friendly)
    ushort4 v = *(const ushort4*)(vrow + l0);
    float4 w = *(const float4*)&saw[l0];
    acc = fmaf(w.x, bf2f(v.x), acc);
    acc = fmaf(w.y, bf2f(v.y), acc);
    acc = fmaf(w.z, bf2f(v.z), acc);
    acc = fmaf(w.w, bf2f(v.w), acc);
  }
  // reduce 32 chunk-lanes within each 32-lane group (shfl_xor stays in group)
#pragma unroll
  for (int off = 16; off > 0; off >>= 1) acc += __shfl_xor(acc, off);
  if (c == 0) out_flat[b * E_ + d * H_ + h] = acc;
}

// ---------------------------------------------------------------------------
// Kernel 3: y[b,o] = bo[o] + sum_j flat[b,j] * Wo[o,j]  (128 blocks)
// ---------------------------------------------------------------------------
__global__ __launch_bounds__(256) void final_proj(
    const float* __restrict__ flat, const float* __restrict__ Wo,
    const float* __restrict__ bo, float* __restrict__ y) {
  __shared__ float sf[E_];
  const int b = blockIdx.y;
  const int o0 = blockIdx.x * 64;
  for (int j = threadIdx.x; j < E_; j += 256) sf[j] = flat[b * E_ + j];
  __syncthreads();
  const int oo = threadIdx.x >> 2, part = threadIdx.x & 3;
  const int o = o0 + oo;
  const float4* wr = (const float4*)(Wo + (size_t)o * E_) + part * 64;
  const float4* fr = (const float4*)sf + part * 64;
  float s = 0.f;
#pragma unroll 8
  for (int i = 0; i < 64; ++i) {
    float4 w = wr[i];
    float4 f = fr[i];
    s += w.x * f.x + w.y * f.y + w.z * f.z + w.w * f.w;
  }
  s += __shfl_xor(s, 1);
  s += __shfl_xor(s, 2);
  if (part == 0) y[b * E_ + o] = s + bo[o];
}

// ---------------------------------------------------------------------------
// Kernel 4: broadcast y (B,E) to out (B,L,E).
// ---------------------------------------------------------------------------
__global__ void broadcast_out(const float* __restrict__ y,
                              float4* __restrict__ out4) {
  const size_t total = (size_t)B_ * L_ * (E_ / 4);
  const float4* y4 = (const float4*)y;
  for (size_t i = (size_t)blockIdx.x * blockDim.x + threadIdx.x; i < total;
       i += (size_t)gridDim.x * blockDim.x) {
    size_t e4 = i & (E_ / 4 - 1);
    size_t b = i >> 20;
    out4[i] = y4[b * (E_ / 4) + e4];
  }
}

// ---------------------------------------------------------------------------
extern "C" void kernel_launch(void* const* d_in, const int* in_sizes, int n_in,
                              void* d_out, int out_size, void* d_ws,
                              size_t ws_size, hipStream_t stream) {
  const float* x  = (const float*)d_in[0];
  const float* Wq = (const float*)d_in[1];
  const float* bq = (const float*)d_in[2];
  const float* Wk = (const float*)d_in[3];
  const float* bk = (const float*)d_in[4];
  const float* Wv = (const float*)d_in[5];
  const float* bv = (const float*)d_in[6];
  const float* Wo = (const float*)d_in[7];
  const float* bo = (const float*)d_in[8];

  char* w = (char*)d_ws;
  unsigned short* KTb  = (unsigned short*)w;
  unsigned short* VTb  = (unsigned short*)(w + 67108864);
  unsigned short* Wb   = (unsigned short*)(w + 134217728);
  float2* Spart        = (float2*)(w + 140509184);
  float* flat          = (float*)(w + 157286400);
  float* y             = (float*)(w + 157319168);
  float* attnW         = (float*)(w + 157351936);
  unsigned short* QTb  = (unsigned short*)d_out;
  unsigned short* xb   = (unsigned short*)((char*)d_out + 67108864);

  conv_w<<<dim3(1024, 3), 256, 0, stream>>>(Wq, Wk, Wv, Wb);
  conv_x<<<dim3(2048), 256, 0, stream>>>(x, xb);
  qkv_gemm8<<<dim3(12, 128), 512, 0, stream>>>(xb, Wb, bq, bk, bv, QTb, KTb,
                                               VTb);
  corr_fft<<<dim3(B_ * H_, 8), 512, 0, stream>>>(QTb, KTb, Spart);
  corr_post<<<dim3(B_ * H_), 1024, 0, stream>>>(Spart, attnW);
  attn_v<<<dim3(B_ * H_, 8), 256, 0, stream>>>(attnW, VTb, flat);
  final_proj<<<dim3(16, B_), 256, 0, stream>>>(flat, Wo, bo, y);
  broadcast_out<<<dim3(2048), 256, 0, stream>>>(y, (float4*)d_out);
}